// Round 12
// baseline (412.332 us; speedup 1.0000x reference)
//
#include <hip/hip_runtime.h>
#include <math.h>

#define HEADS 8
#define NEG 0.2f

// ---- R12 DIAGNOSTIC REPEATS (idempotent kernels; divide observed dur by REP) ----
#define REP_AGGX  5
#define REP_HGEMM 5
#define REP_GEMM2 3
#define REP_AGG2  3

typedef unsigned short ushort_t;
typedef __attribute__((ext_vector_type(8))) short short8;
typedef float f32x4 __attribute__((ext_vector_type(4)));

__device__ inline ushort_t f2bf(float f) {
  union { float f; unsigned u; } v; v.f = f;
  unsigned r = (v.u + 0x7FFF + ((v.u >> 16) & 1)) >> 16;  // RNE
  return (ushort_t)r;
}

__device__ inline float4 bf4(uint2 v) {
  union { unsigned u; float f; } a, b, c, d;
  a.u = v.x << 16; b.u = v.x & 0xffff0000u;
  c.u = v.y << 16; d.u = v.y & 0xffff0000u;
  return make_float4(a.f, b.f, c.f, d.f);
}

// fast ELU: exp(v)-1 via hw v_exp_f32; |abs err| ~1e-7, fine vs 1.7e-3 threshold
__device__ inline float elu_f(float v) {
  return (v > 0.f) ? v : (__expf(v) - 1.f);
}

// async global->LDS, 16B per lane; LDS dest is wave-uniform base + lane*16
#define GLDS16(gp, lp)                                                          \
  __builtin_amdgcn_global_load_lds(                                             \
      (const __attribute__((address_space(1))) void*)(gp),                      \
      (__attribute__((address_space(3))) void*)(lp), 16, 0, 0)

// ---- fused init: W transposes + P projection + zero + x->bf16 ----
__global__ __launch_bounds__(256) void init_k(int* __restrict__ ws, int zero_words,
                                              const float* __restrict__ x,
                                              ushort_t* __restrict__ xb,
                                              const float* __restrict__ W1,
                                              ushort_t* __restrict__ w1t,
                                              const float* __restrict__ W2,
                                              ushort_t* __restrict__ w2t,
                                              const float* __restrict__ as1,
                                              const float* __restrict__ ad1,
                                              float* __restrict__ Ps,
                                              float* __restrict__ Pd, int nx4) {
  __shared__ float tile[32][33];
  int blk = blockIdx.x;
  if (blk < 640) {
    const float* W; ushort_t* Wt; int K, N, tk, tn;
    if (blk < 128) { W = W1; Wt = w1t; K = 128; N = 1024; tk = blk >> 5; tn = blk & 31; }
    else { W = W2; Wt = w2t; K = 1024; N = 512; int t = blk - 128; tk = t >> 4; tn = t & 15; }
    int tx = threadIdx.x & 31, ty = threadIdx.x >> 5;  // 32 x 8
    int k0 = tk * 32, n0 = tn * 32;
#pragma unroll
    for (int r = 0; r < 4; r++)
      tile[ty + r * 8][tx] = W[(size_t)(k0 + ty + r * 8) * N + n0 + tx];  // coalesced read
    __syncthreads();
#pragma unroll
    for (int r = 0; r < 4; r++)
      Wt[(size_t)(n0 + ty + r * 8) * K + k0 + tx] = f2bf(tile[tx][ty + r * 8]);  // coalesced write
  } else if (blk < 648) {
    int h = blk - 640;
    int t = threadIdx.x;
    int k = t >> 1, sd = t & 1;
    const float* att = sd ? ad1 : as1;
    float* P = sd ? Pd : Ps;
    const float* wrow = &W1[(size_t)k * 1024 + h * 128];
    const float* arow = &att[h * 128];
    float s = 0.f;
#pragma unroll 8
    for (int c = 0; c < 128; c++) s += wrow[c] * arow[c];
    P[k * 8 + h] = s;
  } else {
    int i = (blk - 648) * 256 + threadIdx.x;
    if (i < zero_words) ws[i] = 0;
    if (i < nx4) {
      float4 v = ((const float4*)x)[i];
      ushort_t o[4] = {f2bf(v.x), f2bf(v.y), f2bf(v.z), f2bf(v.w)};
      *(uint2*)&xb[i * 4] = *(uint2*)o;
    }
  }
}

// -- edge prep + degree count + batch bounds fused (batch sorted; no atomics) --
__global__ void prep_k(const int* __restrict__ ei, int* __restrict__ src,
                       int* __restrict__ dst, int* __restrict__ deg,
                       const int* __restrict__ batch, int* __restrict__ bstart,
                       int* __restrict__ bend, int E, int Nn) {
  int i = blockIdx.x * blockDim.x + threadIdx.x;
  if (i < Nn) {
    int b = batch[i];
    if (i == 0 || batch[i - 1] != b) bstart[b] = i;
    if (i == Nn - 1 || batch[i + 1] != b) bend[b] = i + 1;
  }
  if (i >= E + Nn) return;
  int s, d;
  if (i < E) { s = ei[i]; d = ei[E + i]; }
  else       { s = d = i - E; }
  src[i] = s;
  dst[i] = d;
  atomicAdd(&deg[d], 1);
}

// single-block scan over N, 4 elems/thread (4096/chunk), wave-shuffle based
__global__ __launch_bounds__(1024) void scan_k(const int* __restrict__ deg,
                                               int* __restrict__ offs,
                                               int* __restrict__ cursor, int Nn) {
  __shared__ int wtot[16];
  __shared__ int wexcl[16];
  __shared__ int soff_s;
  int t = threadIdx.x;
  int lane = t & 63, w = t >> 6;
  if (t == 0) soff_s = 0;
  __syncthreads();
  for (int base = 0; base < Nn; base += 4096) {
    int idx = base + 4 * t;
    int4 v = make_int4(0, 0, 0, 0);
    if (idx + 3 < Nn) v = *(const int4*)&deg[idx];
    else {
      if (idx < Nn)     v.x = deg[idx];
      if (idx + 1 < Nn) v.y = deg[idx + 1];
      if (idx + 2 < Nn) v.z = deg[idx + 2];
      if (idx + 3 < Nn) v.w = deg[idx + 3];
    }
    int s1 = v.x, s2 = s1 + v.y, s3 = s2 + v.z, s4 = s3 + v.w;
    int sc = s4;  // wave-inclusive scan of per-thread totals
#pragma unroll
    for (int o = 1; o < 64; o <<= 1) {
      int x = __shfl_up(sc, o);
      if (lane >= o) sc += x;
    }
    if (lane == 63) wtot[w] = sc;
    __syncthreads();
    if (w == 0) {
      int tv = (lane < 16) ? wtot[lane] : 0;
      int ts = tv;
#pragma unroll
      for (int o = 1; o < 16; o <<= 1) {
        int x = __shfl_up(ts, o);
        if (lane >= o) ts += x;
      }
      if (lane < 16) wexcl[lane] = ts - tv;
      if (lane == 15) wtot[15] = ts;  // chunk total
    }
    __syncthreads();
    int excl = soff_s + wexcl[w] + (sc - s4);
    int o0 = excl, o1 = excl + s1, o2 = excl + s2, o3 = excl + s3;
    if (idx < Nn)     { offs[idx] = o0;     cursor[idx] = o0; }
    if (idx + 1 < Nn) { offs[idx + 1] = o1; cursor[idx + 1] = o1; }
    if (idx + 2 < Nn) { offs[idx + 2] = o2; cursor[idx + 2] = o2; }
    if (idx + 3 < Nn) { offs[idx + 3] = o3; cursor[idx + 3] = o3; }
    int chunk_total = wtot[15];
    __syncthreads();
    if (t == 0) soff_s += chunk_total;
    __syncthreads();
  }
  if (t == 0) offs[Nn] = soff_s;
}

// scatter src into CSR slot order; tail blocks (>= eb) run the layer-1 alpha GEMV
__global__ __launch_bounds__(256) void scatter_k(const int* __restrict__ src,
                                                 const int* __restrict__ dst,
                                                 int* __restrict__ cursor,
                                                 int* __restrict__ psrc, int Etot, int eb,
                                                 const float* __restrict__ x,
                                                 const float* __restrict__ Ps,
                                                 const float* __restrict__ Pd,
                                                 float* __restrict__ asrc,
                                                 float* __restrict__ adst, int Nn) {
  if ((int)blockIdx.x >= eb) {
    __shared__ float ps[1024], pd[1024];
    int t = threadIdx.x;
    for (int i = t; i < 1024; i += 256) { ps[i] = Ps[i]; pd[i] = Pd[i]; }
    __syncthreads();
    int n = (blockIdx.x - eb) * 256 + t;
    if (n >= Nn) return;
    const float4* xr = (const float4*)&x[(size_t)n * 128];
    float as[8], ad[8];
#pragma unroll
    for (int h = 0; h < 8; h++) { as[h] = 0.f; ad[h] = 0.f; }
    for (int k4 = 0; k4 < 32; k4++) {
      float4 xv = xr[k4];
      float xs[4] = {xv.x, xv.y, xv.z, xv.w};
#pragma unroll
      for (int j = 0; j < 4; j++) {
        int k = k4 * 4 + j;
#pragma unroll
        for (int h = 0; h < 8; h++) {
          as[h] += xs[j] * ps[k * 8 + h];
          ad[h] += xs[j] * pd[k * 8 + h];
        }
      }
    }
#pragma unroll
    for (int h = 0; h < 8; h++) {
      asrc[n * 8 + h] = as[h];
      adst[n * 8 + h] = ad[h];
    }
    return;
  }
  int i = blockIdx.x * 256 + threadIdx.x;
  if (i >= Etot) return;
  int p = atomicAdd(&cursor[dst[i]], 1);
  psrc[p] = src[i];
}

// ---- layer-1 x-side aggregation (gathers x, 256B/edge) ----
__global__ __launch_bounds__(64) void aggx_k(const ushort_t* __restrict__ xb,
                                             const float* __restrict__ asrc,
                                             const float* __restrict__ adst,
                                             const int* __restrict__ offs,
                                             const int* __restrict__ psrc,
                                             ushort_t* __restrict__ sb, int Nn) {
  int n = blockIdx.x;
  int l = threadIdx.x;
  int u_mine = l >> 3, h_mine = l & 7;
  float adn = adst[n * 8 + h_mine];
  int e0 = offs[n], e1 = offs[n + 1];
  int c0 = l * 2;

  for (int rep = 0; rep < REP_AGGX; ++rep) {  // DIAG: idempotent repeat
    float acc0[8], acc1[8], wsum[8];
#pragma unroll
    for (int h = 0; h < 8; h++) { acc0[h] = 0.f; acc1[h] = 0.f; wsum[h] = 0.f; }

    for (int i = e0; i < e1; i += 8) {
      int bs = min(8, e1 - i);
      int eu = i + (u_mine < bs ? u_mine : bs - 1);
      int se = psrc[eu];
      float v = asrc[se * 8 + h_mine] + adn;
      v = (v > 0.f) ? v : NEG * v;
      float wm = __expf(v);
      int ss[8];
      unsigned xvv[8];
#pragma unroll
      for (int u = 0; u < 8; u++) ss[u] = psrc[i + (u < bs ? u : bs - 1)];
#pragma unroll
      for (int u = 0; u < 8; u++) xvv[u] = *(const unsigned*)&xb[(size_t)ss[u] * 128 + c0];
#pragma unroll
      for (int u = 0; u < 8; u++) {
        if (u < bs) {
          union { unsigned u; float f; } a, b;
          a.u = xvv[u] << 16; b.u = xvv[u] & 0xffff0000u;
#pragma unroll
          for (int h = 0; h < 8; h++) {
            float w = __shfl(wm, (u << 3) | h);
            acc0[h] += w * a.f;
            acc1[h] += w * b.f;
            wsum[h] += w;
          }
        }
      }
    }

#pragma unroll
    for (int h = 0; h < 8; h++) {
      float inv = 1.f / wsum[h];
      unsigned pr = (unsigned)f2bf(acc0[h] * inv) | ((unsigned)f2bf(acc1[h] * inv) << 16);
      *(unsigned*)&sb[(size_t)n * 1024 + h * 128 + c0] = pr;
    }
  }
}

// ---- head-blocked GEMM: g1[n, h*128+j] = elu( s[n,h,:] . W1[:, h*128+j] + b1 ) ----
__global__ __launch_bounds__(256) void hgemm_k(const ushort_t* __restrict__ S,
                                               const ushort_t* __restrict__ Wt,
                                               const float* __restrict__ bias,
                                               ushort_t* __restrict__ G, int M) {
  __shared__ __attribute__((aligned(16))) ushort_t lds[32768];
  int tid = threadIdx.x;
  int lane = tid & 63;
  int wave = tid >> 6;
  int wm = (wave >> 1) * 64, wn = (wave & 1) * 64;
  int head = blockIdx.x;
  int hb0 = head * 128;
  int bm = blockIdx.y * 128;
  int lrow = lane & 15, lq = lane >> 4;

  int srow = lane >> 3;
  int scol = 8 * ((lane & 7) ^ srow);
  const ushort_t* pa[4];
  const ushort_t* pb[4];
  int lofs[4];
#pragma unroll
  for (int c = 0; c < 4; c++) {
    int row = wave * 32 + c * 8 + srow;
    int ga = min(bm + row, M - 1);
    pa[c] = &S[(size_t)ga * 1024 + hb0 + scol];
    pb[c] = &Wt[(size_t)(hb0 + row) * 128 + scol];
    lofs[c] = (wave * 4 + c) * 512;
  }

  auto stage = [&](int buf, int k0) {
#pragma unroll
    for (int c = 0; c < 4; c++) GLDS16(pa[c] + k0, &lds[buf * 8192 + lofs[c]]);
#pragma unroll
    for (int c = 0; c < 4; c++) GLDS16(pb[c] + k0, &lds[16384 + buf * 8192 + lofs[c]]);
  };

  for (int rep = 0; rep < REP_HGEMM; ++rep) {  // DIAG: idempotent repeat
    __syncthreads();  // rep boundary: epilogue LDS reads done before re-staging
    f32x4 acc[4][4];
#pragma unroll
    for (int i = 0; i < 4; i++)
#pragma unroll
      for (int j = 0; j < 4; j++) acc[i][j] = 0.f;

    auto compute = [&](int buf) {
      const ushort_t* Asb = &lds[buf * 8192];
      const ushort_t* Bsb = &lds[16384 + buf * 8192];
#pragma unroll
      for (int ks = 0; ks < 2; ks++) {
        short8 af[4], bfr[4];
#pragma unroll
        for (int t = 0; t < 4; t++) {
          int cbs = (ks * 64 + lq * 16) ^ ((lrow & 7) << 4);
          af[t]  = *(const short8*)&Asb[(wm + t * 16 + lrow) * 64 + (cbs >> 1)];
          bfr[t] = *(const short8*)&Bsb[(wn + t * 16 + lrow) * 64 + (cbs >> 1)];
        }
#pragma unroll
        for (int i = 0; i < 4; i++)
#pragma unroll
          for (int j = 0; j < 4; j++)
            acc[i][j] = __builtin_amdgcn_mfma_f32_16x16x32_bf16(af[i], bfr[j], acc[i][j], 0, 0, 0);
      }
    };

    stage(0, 0);
    asm volatile("s_waitcnt vmcnt(0)" ::: "memory");
    __builtin_amdgcn_s_barrier();
    stage(1, 64);
    compute(0);
    asm volatile("s_waitcnt vmcnt(0)" ::: "memory");
    __builtin_amdgcn_s_barrier();
    compute(1);

    __syncthreads();

    ushort_t* Cl = lds;  // [128][136]
    float bv[4];
#pragma unroll
    for (int j = 0; j < 4; j++) bv[j] = bias[hb0 + wn + j * 16 + lrow];
#pragma unroll
    for (int i = 0; i < 4; i++) {
#pragma unroll
      for (int j = 0; j < 4; j++) {
        int col = wn + j * 16 + lrow;
#pragma unroll
        for (int r = 0; r < 4; r++) {
          int row = wm + i * 16 + lq * 4 + r;
          Cl[row * 136 + col] = f2bf(elu_f(acc[i][j][r] + bv[j]));
        }
      }
    }
    __syncthreads();
#pragma unroll
    for (int p = 0; p < 8; p++) {
      int row = p * 16 + (tid >> 4);
      int col8 = (tid & 15) * 8;
      if (bm + row < M)
        *(uint4*)&G[(size_t)(bm + row) * 1024 + hb0 + col8] = *(const uint4*)&Cl[row * 136 + col8];
    }
  }
}

// ------- layer-2 GEMM, BN=64, dbuf GLDS pipeline, fixed epilogue -------
__global__ __launch_bounds__(256) void mfma_gemm_k(const ushort_t* __restrict__ A,
                                                   const ushort_t* __restrict__ Bt,
                                                   ushort_t* __restrict__ Cb,
                                                   const float* __restrict__ att_s,
                                                   const float* __restrict__ att_d,
                                                   float* __restrict__ asrc,
                                                   float* __restrict__ adst,
                                                   int M, int N, int K, int CSHIFT) {
  __shared__ __attribute__((aligned(16))) ushort_t lds[24576];  // 48KB multi-use
  int tid = threadIdx.x;
  int lane = tid & 63;
  int wave = tid >> 6;
  int wm = (wave >> 1) * 64, wn = (wave & 1) * 32;
  int bm = blockIdx.y * 128, bn = blockIdx.x * 64;
  int lrow = lane & 15, lq = lane >> 4;

  int srow = lane >> 3;
  int scol = 8 * ((lane & 7) ^ srow);
  const ushort_t* pa[4];
  int laofs[4];
#pragma unroll
  for (int c = 0; c < 4; c++) {
    int row = wave * 32 + c * 8 + srow;
    int ga = min(bm + row, M - 1);
    pa[c] = &A[(size_t)ga * K + scol];
    laofs[c] = (wave * 4 + c) * 512;
  }
  const ushort_t* pb[2];
  int lbofs[2];
#pragma unroll
  for (int c = 0; c < 2; c++) {
    int row = wave * 16 + c * 8 + srow;
    pb[c] = &Bt[(size_t)(bn + row) * K + scol];
    lbofs[c] = (wave * 2 + c) * 512;
  }

  auto stage = [&](int buf, int k0) {
#pragma unroll
    for (int c = 0; c < 4; c++) GLDS16(pa[c] + k0, &lds[buf * 8192 + laofs[c]]);
#pragma unroll
    for (int c = 0; c < 2; c++) GLDS16(pb[c] + k0, &lds[16384 + buf * 4096 + lbofs[c]]);
  };

  for (int rep = 0; rep < REP_GEMM2; ++rep) {  // DIAG: idempotent repeat
    __syncthreads();  // rep boundary: epilogue LDS reads done before re-staging
    f32x4 acc[4][2];
#pragma unroll
    for (int i = 0; i < 4; i++)
#pragma unroll
      for (int j = 0; j < 2; j++) acc[i][j] = 0.f;

    auto compute = [&](int buf) {
      const ushort_t* Asb = &lds[buf * 8192];
      const ushort_t* Bsb = &lds[16384 + buf * 4096];
#pragma unroll
      for (int ks = 0; ks < 2; ks++) {
        int cbs = (ks * 64 + lq * 16) ^ ((lrow & 7) << 4);
        short8 af[4], bfr[2];
#pragma unroll
        for (int t = 0; t < 4; t++)
          af[t]  = *(const short8*)&Asb[(wm + t * 16 + lrow) * 64 + (cbs >> 1)];
#pragma unroll
        for (int t = 0; t < 2; t++)
          bfr[t] = *(const short8*)&Bsb[(wn + t * 16 + lrow) * 64 + (cbs >> 1)];
#pragma unroll
        for (int i = 0; i < 4; i++)
#pragma unroll
          for (int j = 0; j < 2; j++)
            acc[i][j] = __builtin_amdgcn_mfma_f32_16x16x32_bf16(af[i], bfr[j], acc[i][j], 0, 0, 0);
      }
    };

    int NT = K >> 6;
    stage(0, 0);
    asm volatile("s_waitcnt vmcnt(0)" ::: "memory");
    __builtin_amdgcn_s_barrier();
    int cur = 0;
    for (int t = 0; t + 1 < NT; ++t) {
      stage(cur ^ 1, (t + 1) << 6);
      compute(cur);
      asm volatile("s_waitcnt vmcnt(0)" ::: "memory");
      __builtin_amdgcn_s_barrier();
      cur ^= 1;
    }
    compute(cur);

    __syncthreads();

    ushort_t* Cl = lds;                       // [128][72]
    float* pls = (float*)&lds[20480];
    float* pld = pls + 256;

    int hh = bn >> CSHIFT;
    {
      float avs[2], avd[2];
#pragma unroll
      for (int j = 0; j < 2; j++) {
        int col = bn + wn + j * 16 + lrow;
        avs[j] = att_s[col];
        avd[j] = att_d[col];
      }
#pragma unroll
      for (int i = 0; i < 4; i++) {
#pragma unroll
        for (int r = 0; r < 4; r++) {
          float ps = 0.f, pd = 0.f;
#pragma unroll
          for (int j = 0; j < 2; j++) {
            float v = acc[i][j][r];
            ps += v * avs[j];
            pd += v * avd[j];
          }
#pragma unroll
          for (int o = 1; o < 16; o <<= 1) {
            ps += __shfl_xor(ps, o);
            pd += __shfl_xor(pd, o);
          }
          if (lrow == 0) {
            int rr = i * 16 + lq * 4 + r;
            pls[wave * 64 + rr] = ps;
            pld[wave * 64 + rr] = pd;
          }
        }
      }
    }

#pragma unroll
    for (int i = 0; i < 4; i++) {
#pragma unroll
      for (int j = 0; j < 2; j++) {
        int col = wn + j * 16 + lrow;
#pragma unroll
        for (int r = 0; r < 4; r++) {
          int row = wm + i * 16 + lq * 4 + r;
          Cl[row * 72 + col] = f2bf(acc[i][j][r]);
        }
      }
    }
    __syncthreads();

#pragma unroll
    for (int p = 0; p < 4; p++) {
      int row = p * 32 + (tid >> 3);
      int col8 = (tid & 7) * 8;
      if (bm + row < M)
        *(uint4*)&Cb[(size_t)(bm + row) * N + bn + col8] = *(const uint4*)&Cl[row * 72 + col8];
    }

    {
      int r = tid & 127, half = tid >> 7;
      if (bm + r < M) {
        const float* P = half ? pld : pls;
        float* O = half ? adst : asrc;
        int w0 = (r >> 6) * 2, idx = r & 63;
        O[(size_t)(bm + r) * HEADS + hh] = P[w0 * 64 + idx] + P[(w0 + 1) * 64 + idx];
      }
    }
  }
}

// ---- CSR aggregation (layer 2): depth-2 pipelined gathers + wave alpha sharing ----
template <int F, int CSHIFT, int BT, int NSPLIT, typename OT>
__global__ __launch_bounds__(BT) void aggregate_k(const ushort_t* __restrict__ hb,
                                                  const float* __restrict__ asrc,
                                                  const float* __restrict__ adst,
                                                  const int* __restrict__ offs,
                                                  const int* __restrict__ psrc,
                                                  const float* __restrict__ bias,
                                                  OT* __restrict__ out) {
  constexpr int CPB = F / NSPLIT;
  constexpr int G = (1 << CSHIFT) >> 2;
  static_assert(CPB == 4 * BT, "CPB/thread mismatch");
  static_assert(G >= 8 && G <= 64, "head group must cover the 8-edge batch");
  int nb = blockIdx.x;
  int n = nb / NSPLIT;
  int coff = (nb - n * NSPLIT) * CPB;
  int t = threadIdx.x;
  int c0 = coff + 4 * t;
  int hh = c0 >> CSHIFT;
  int lane = t & 63;
  int sub = lane & (G - 1);
  int gb = lane & ~(G - 1);
  float adn = adst[n * HEADS + hh];
  int e0 = offs[n], e1 = offs[n + 1];

  for (int rep = 0; rep < REP_AGG2; ++rep) {  // DIAG: idempotent repeat
    float4 acc = make_float4(0.f, 0.f, 0.f, 0.f);
    float wsum = 0.f;

    int i = e0;
    uint2 rA[8];
    float myWA = 0.f;
    bool haveA = (i + 8 <= e1);
    if (haveA) {
      int sA[8];
#pragma unroll
      for (int u = 0; u < 8; u++) sA[u] = psrc[i + u];
#pragma unroll
      for (int u = 0; u < 8; u++) rA[u] = *(const uint2*)&hb[(size_t)sA[u] * F + c0];
      int ms = psrc[i + (sub < 8 ? sub : 0)];
      float v = asrc[ms * HEADS + hh] + adn;
      v = (v > 0.f) ? v : NEG * v;
      myWA = __expf(v);
    }
    while (i + 16 <= e1) {
      int sB[8];
      uint2 rB[8];
#pragma unroll
      for (int u = 0; u < 8; u++) sB[u] = psrc[i + 8 + u];
#pragma unroll
      for (int u = 0; u < 8; u++) rB[u] = *(const uint2*)&hb[(size_t)sB[u] * F + c0];
      int ms = psrc[i + 8 + (sub < 8 ? sub : 0)];
      float vb = asrc[ms * HEADS + hh] + adn;
      vb = (vb > 0.f) ? vb : NEG * vb;
      float myWB = __expf(vb);
#pragma unroll
      for (int u = 0; u < 8; u++) {
        float w = __shfl(myWA, gb + u);
        float4 f = bf4(rA[u]);
        wsum += w;
        acc.x += w * f.x;
        acc.y += w * f.y;
        acc.z += w * f.z;
        acc.w += w * f.w;
      }
      i += 8;
#pragma unroll
      for (int u = 0; u < 8; u++) rA[u] = rB[u];
      myWA = myWB;
    }
    if (haveA) {
#pragma unroll
      for (int u = 0; u < 8; u++) {
        float w = __shfl(myWA, gb + u);
        float4 f = bf4(rA[u]);
        wsum += w;
        acc.x += w * f.x;
        acc.y += w * f.y;
        acc.z += w * f.z;
        acc.w += w * f.w;
      }
      i += 8;
    }
    for (; i < e1; i++) {
      int ss = psrc[i];
      float v = asrc[ss * HEADS + hh] + adn;
      v = (v > 0.f) ? v : NEG * v;
      float w = __expf(v);
      float4 f = bf4(*(const uint2*)&hb[(size_t)ss * F + c0]);
      wsum += w;
      acc.x += w * f.x; acc.y += w * f.y;
      acc.z += w * f.z; acc.w += w * f.w;
    }

    float inv = 1.f / wsum;
    float v0 = elu_f(acc.x * inv + bias[c0]);
    float v1 = elu_f(acc.y * inv + bias[c0 + 1]);
    float v2 = elu_f(acc.z * inv + bias[c0 + 2]);
    float v3 = elu_f(acc.w * inv + bias[c0 + 3]);
    if constexpr (sizeof(OT) == 2) {
      unsigned p0 = (unsigned)f2bf(v0) | ((unsigned)f2bf(v1) << 16);
      unsigned p1 = (unsigned)f2bf(v2) | ((unsigned)f2bf(v3) << 16);
      *(uint2*)&((ushort_t*)out)[(size_t)n * F + c0] = make_uint2(p0, p1);
    } else {
      *(float4*)&((float*)out)[(size_t)n * F + c0] = make_float4(v0, v1, v2, v3);
    }
  }
}

__global__ __launch_bounds__(256) void pool_k(const float* __restrict__ g,
                                              const int* __restrict__ batch,
                                              float* __restrict__ sums, int Nn) {
  int c = blockIdx.x * 256 + threadIdx.x;  // 0..511
  int n0 = blockIdx.y * 50;
  int n1 = min(n0 + 50, Nn);
  if (n0 >= n1) return;
  float acc = 0.f;
  int cur = batch[n0];
  for (int n = n0; n < n1; n++) {
    int b = batch[n];
    if (b != cur) { atomicAdd(&sums[cur * 512 + c], acc); acc = 0.f; cur = b; }
    acc += g[(size_t)n * 512 + c];
  }
  atomicAdd(&sums[cur * 512 + c], acc);
}

// ---------------- mean + fc1(elu) + fc2, one block ----------------
__global__ __launch_bounds__(512) void mlp_k(const float* __restrict__ sums,
                                             const int* __restrict__ bstart,
                                             const int* __restrict__ bend,
                                             const float* __restrict__ w1,
                                             const float* __restrict__ b1,
                                             const float* __restrict__ w2,
                                             const float* __restrict__ b2,
                                             float* __restrict__ out) {
  __shared__ float gm[16 * 512];
  __shared__ float t1[16 * 32];
  int t = threadIdx.x;
  for (int i = t; i < 16 * 512; i += 512) {
    int b = i >> 9;
    float c = (float)(bend[b] - bstart[b]);
    gm[i] = sums[i] / fmaxf(c, 1.f);
  }
  __syncthreads();
  {
    int b = t >> 5, j = t & 31;
    float s = b1[j];
    for (int k = 0; k < 512; k++) s += gm[(b << 9) + k] * w1[k * 32 + j];
    t1[t] = elu_f(s);
  }
  __syncthreads();
  if (t < 160) {
    int b = t / 10, j = t - b * 10;
    float s = b2[j];
#pragma unroll
    for (int k = 0; k < 32; k++) s += t1[b * 32 + k] * w2[k * 10 + j];
    out[t] = s;
  }
}

extern "C" void kernel_launch(void* const* d_in, const int* in_sizes, int n_in,
                              void* d_out, int out_size, void* d_ws, size_t ws_size,
                              hipStream_t stream) {
  const float* x   = (const float*)d_in[0];
  const int*   ei  = (const int*)d_in[1];
  const int* batch = (const int*)d_in[2];
  const float* W1  = (const float*)d_in[3];
  const float* as1 = (const float*)d_in[4];
  const float* ad1 = (const float*)d_in[5];
  const float* b1  = (const float*)d_in[6];
  const float* W2  = (const float*)d_in[7];
  const float* as2 = (const float*)d_in[8];
  const float* ad2 = (const float*)d_in[9];
  const float* b2  = (const float*)d_in[10];
  const float* f1w = (const float*)d_in[11];
  const float* f1b = (const float*)d_in[12];
  const float* f2w = (const float*)d_in[13];
  const float* f2b = (const float*)d_in[14];
  float* out = (float*)d_out;

  const int Nn = in_sizes[2];      // 10000
  const int E = in_sizes[1] / 2;   // 160000
  const int Etot = E + Nn;         // self loops appended

  // ---- workspace layout (4B words, 64-word aligned) ----
  size_t off = 0;
  auto alloc = [&](size_t elems) { size_t o = off; off += (elems + 63) & ~(size_t)63; return o; };
  int* wsi = (int*)d_ws;
  float* wsf = (float*)d_ws;

  size_t o_deg  = alloc(Nn);
  size_t o_pool = alloc(16 * 512);
  size_t zero_words = off;               // only deg+pool accumulate -> zero each call
  size_t o_as1  = alloc((size_t)Nn * 8);
  size_t o_ad1  = alloc((size_t)Nn * 8);
  size_t o_as2  = alloc((size_t)Nn * 8);
  size_t o_ad2  = alloc((size_t)Nn * 8);
  size_t o_ps   = alloc(1024);           // P projections [128][8] fp32
  size_t o_pd   = alloc(1024);
  size_t o_bst  = alloc(64);
  size_t o_ben  = alloc(64);
  size_t o_offs = alloc(Nn + 1);
  size_t o_cur  = alloc(Nn);
  size_t o_src  = alloc(Etot);
  size_t o_dst  = alloc(Etot);
  size_t o_psrc = alloc(Etot);
  size_t o_xb   = alloc((size_t)Nn * 128 / 2);   // x bf16  [N,128]
  size_t o_w1t  = alloc(1024 * 128 / 2);         // W1^T bf16 [1024,128]
  size_t o_w2t  = alloc(512 * 1024 / 2);         // W2^T bf16 [512,1024]
  size_t o_s    = alloc((size_t)Nn * 1024 / 2);  // s bf16 [N,1024]
  size_t o_h    = alloc((size_t)Nn * 1024 / 2);  // h2 bf16 [N,512] (first half)
  size_t o_g    = alloc((size_t)Nn * 1024);      // g1 bf16 (first half) then g2 fp32

  ushort_t* xb  = (ushort_t*)(wsi + o_xb);
  ushort_t* w1t = (ushort_t*)(wsi + o_w1t);
  ushort_t* w2t = (ushort_t*)(wsi + o_w2t);
  ushort_t* sb  = (ushort_t*)(wsi + o_s);
  ushort_t* hb  = (ushort_t*)(wsi + o_h);
  ushort_t* g1b = (ushort_t*)(wsi + o_g);

  int eb = (Etot + 255) / 256;
  int ab = (Nn + 255) / 256;  // al1 tail blocks on scatter grid

  int nx4 = Nn * 128 / 4;
  int ep_work = (int)((zero_words > (size_t)nx4 ? zero_words : (size_t)nx4));
  int init_blocks = 648 + (ep_work + 255) / 256;
  init_k<<<init_blocks, 256, 0, stream>>>(wsi, (int)zero_words, x, xb,
                                          W1, w1t, W2, w2t,
                                          as1, ad1, wsf + o_ps, wsf + o_pd, nx4);
  prep_k<<<eb, 256, 0, stream>>>(ei, wsi + o_src, wsi + o_dst, wsi + o_deg,
                                 batch, wsi + o_bst, wsi + o_ben, E, Nn);
  scan_k<<<1, 1024, 0, stream>>>(wsi + o_deg, wsi + o_offs, wsi + o_cur, Nn);
  scatter_k<<<eb + ab, 256, 0, stream>>>(wsi + o_src, wsi + o_dst, wsi + o_cur,
                                         wsi + o_psrc, Etot, eb,
                                         x, wsf + o_ps, wsf + o_pd,
                                         wsf + o_as1, wsf + o_ad1, Nn);

  // ---- layer 1 (restructured): aggregate x; head-blocked GEMM ----
  aggx_k<<<Nn, 64, 0, stream>>>(xb, wsf + o_as1, wsf + o_ad1,
                                wsi + o_offs, wsi + o_psrc, sb, Nn);
  hgemm_k<<<dim3(8, (Nn + 127) / 128), 256, 0, stream>>>(sb, w1t, b1, g1b, Nn);

  // ---- layer 2: 1024 -> 8x64 (BN=64 tile) ----
  mfma_gemm_k<<<dim3(512 / 64, (Nn + 127) / 128), 256, 0, stream>>>(
      g1b, w2t, hb, as2, ad2, wsf + o_as2, wsf + o_ad2, Nn, 512, 1024, 6);
  aggregate_k<512, 6, 64, 2, float><<<Nn * 2, 64, 0, stream>>>(
      hb, wsf + o_as2, wsf + o_ad2, wsi + o_offs, wsi + o_psrc, b2, wsf + o_g);

  // ---- pool + MLP ----
  pool_k<<<dim3(2, (Nn + 49) / 50), 256, 0, stream>>>(wsf + o_g, batch, wsf + o_pool, Nn);
  mlp_k<<<1, 512, 0, stream>>>(wsf + o_pool, wsi + o_bst, wsi + o_ben, f1w, f1b, f2w, f2b, out);
}

// Round 13
// 261.737 us; speedup vs baseline: 1.5754x; 1.5754x over previous
//
#include <hip/hip_runtime.h>
#include <math.h>

#define HEADS 8
#define NEG 0.2f

typedef unsigned short ushort_t;
typedef __attribute__((ext_vector_type(8))) short short8;
typedef float f32x4 __attribute__((ext_vector_type(4)));

__device__ inline ushort_t f2bf(float f) {
  union { float f; unsigned u; } v; v.f = f;
  unsigned r = (v.u + 0x7FFF + ((v.u >> 16) & 1)) >> 16;  // RNE
  return (ushort_t)r;
}

__device__ inline float4 bf4(uint2 v) {
  union { unsigned u; float f; } a, b, c, d;
  a.u = v.x << 16; b.u = v.x & 0xffff0000u;
  c.u = v.y << 16; d.u = v.y & 0xffff0000u;
  return make_float4(a.f, b.f, c.f, d.f);
}

// fast ELU: exp(v)-1 via hw v_exp_f32; |abs err| ~1e-7, fine vs 1.7e-3 threshold
__device__ inline float elu_f(float v) {
  return (v > 0.f) ? v : (__expf(v) - 1.f);
}

// async global->LDS, 16B per lane; LDS dest is wave-uniform base + lane*16
#define GLDS16(gp, lp)                                                          \
  __builtin_amdgcn_global_load_lds(                                             \
      (const __attribute__((address_space(1))) void*)(gp),                      \
      (__attribute__((address_space(3))) void*)(lp), 16, 0, 0)

// ---- fused init: W transposes + P projection + zero + x->bf16 ----
__global__ __launch_bounds__(256) void init_k(int* __restrict__ ws, int zero_words,
                                              const float* __restrict__ x,
                                              ushort_t* __restrict__ xb,
                                              const float* __restrict__ W1,
                                              ushort_t* __restrict__ w1t,
                                              const float* __restrict__ W2,
                                              ushort_t* __restrict__ w2t,
                                              const float* __restrict__ as1,
                                              const float* __restrict__ ad1,
                                              float* __restrict__ Ps,
                                              float* __restrict__ Pd, int nx4) {
  __shared__ float tile[32][33];
  int blk = blockIdx.x;
  if (blk < 640) {
    const float* W; ushort_t* Wt; int K, N, tk, tn;
    if (blk < 128) { W = W1; Wt = w1t; K = 128; N = 1024; tk = blk >> 5; tn = blk & 31; }
    else { W = W2; Wt = w2t; K = 1024; N = 512; int t = blk - 128; tk = t >> 4; tn = t & 15; }
    int tx = threadIdx.x & 31, ty = threadIdx.x >> 5;  // 32 x 8
    int k0 = tk * 32, n0 = tn * 32;
#pragma unroll
    for (int r = 0; r < 4; r++)
      tile[ty + r * 8][tx] = W[(size_t)(k0 + ty + r * 8) * N + n0 + tx];  // coalesced read
    __syncthreads();
#pragma unroll
    for (int r = 0; r < 4; r++)
      Wt[(size_t)(n0 + ty + r * 8) * K + k0 + tx] = f2bf(tile[tx][ty + r * 8]);  // coalesced write
  } else if (blk < 648) {
    int h = blk - 640;
    int t = threadIdx.x;
    int k = t >> 1, sd = t & 1;
    const float* att = sd ? ad1 : as1;
    float* P = sd ? Pd : Ps;
    const float* wrow = &W1[(size_t)k * 1024 + h * 128];
    const float* arow = &att[h * 128];
    float s = 0.f;
#pragma unroll 8
    for (int c = 0; c < 128; c++) s += wrow[c] * arow[c];
    P[k * 8 + h] = s;
  } else {
    int i = (blk - 648) * 256 + threadIdx.x;
    if (i < zero_words) ws[i] = 0;
    if (i < nx4) {
      float4 v = ((const float4*)x)[i];
      ushort_t o[4] = {f2bf(v.x), f2bf(v.y), f2bf(v.z), f2bf(v.w)};
      *(uint2*)&xb[i * 4] = *(uint2*)o;
    }
  }
}

// -- edge prep + degree count + batch bounds fused (batch sorted; no atomics) --
__global__ void prep_k(const int* __restrict__ ei, int* __restrict__ src,
                       int* __restrict__ dst, int* __restrict__ deg,
                       const int* __restrict__ batch, int* __restrict__ bstart,
                       int* __restrict__ bend, int E, int Nn) {
  int i = blockIdx.x * blockDim.x + threadIdx.x;
  if (i < Nn) {
    int b = batch[i];
    if (i == 0 || batch[i - 1] != b) bstart[b] = i;
    if (i == Nn - 1 || batch[i + 1] != b) bend[b] = i + 1;
  }
  if (i >= E + Nn) return;
  int s, d;
  if (i < E) { s = ei[i]; d = ei[E + i]; }
  else       { s = d = i - E; }
  src[i] = s;
  dst[i] = d;
  atomicAdd(&deg[d], 1);
}

// single-block scan over N, 4 elems/thread (4096/chunk), wave-shuffle based
__global__ __launch_bounds__(1024) void scan_k(const int* __restrict__ deg,
                                               int* __restrict__ offs,
                                               int* __restrict__ cursor, int Nn) {
  __shared__ int wtot[16];
  __shared__ int wexcl[16];
  __shared__ int soff_s;
  int t = threadIdx.x;
  int lane = t & 63, w = t >> 6;
  if (t == 0) soff_s = 0;
  __syncthreads();
  for (int base = 0; base < Nn; base += 4096) {
    int idx = base + 4 * t;
    int4 v = make_int4(0, 0, 0, 0);
    if (idx + 3 < Nn) v = *(const int4*)&deg[idx];
    else {
      if (idx < Nn)     v.x = deg[idx];
      if (idx + 1 < Nn) v.y = deg[idx + 1];
      if (idx + 2 < Nn) v.z = deg[idx + 2];
      if (idx + 3 < Nn) v.w = deg[idx + 3];
    }
    int s1 = v.x, s2 = s1 + v.y, s3 = s2 + v.z, s4 = s3 + v.w;
    int sc = s4;  // wave-inclusive scan of per-thread totals
#pragma unroll
    for (int o = 1; o < 64; o <<= 1) {
      int x = __shfl_up(sc, o);
      if (lane >= o) sc += x;
    }
    if (lane == 63) wtot[w] = sc;
    __syncthreads();
    if (w == 0) {
      int tv = (lane < 16) ? wtot[lane] : 0;
      int ts = tv;
#pragma unroll
      for (int o = 1; o < 16; o <<= 1) {
        int x = __shfl_up(ts, o);
        if (lane >= o) ts += x;
      }
      if (lane < 16) wexcl[lane] = ts - tv;
      if (lane == 15) wtot[15] = ts;  // chunk total
    }
    __syncthreads();
    int excl = soff_s + wexcl[w] + (sc - s4);
    int o0 = excl, o1 = excl + s1, o2 = excl + s2, o3 = excl + s3;
    if (idx < Nn)     { offs[idx] = o0;     cursor[idx] = o0; }
    if (idx + 1 < Nn) { offs[idx + 1] = o1; cursor[idx + 1] = o1; }
    if (idx + 2 < Nn) { offs[idx + 2] = o2; cursor[idx + 2] = o2; }
    if (idx + 3 < Nn) { offs[idx + 3] = o3; cursor[idx + 3] = o3; }
    int chunk_total = wtot[15];
    __syncthreads();
    if (t == 0) soff_s += chunk_total;
    __syncthreads();
  }
  if (t == 0) offs[Nn] = soff_s;
}

// scatter src into CSR slot order; tail blocks (>= eb) run the layer-1 alpha GEMV
__global__ __launch_bounds__(256) void scatter_k(const int* __restrict__ src,
                                                 const int* __restrict__ dst,
                                                 int* __restrict__ cursor,
                                                 int* __restrict__ psrc, int Etot, int eb,
                                                 const float* __restrict__ x,
                                                 const float* __restrict__ Ps,
                                                 const float* __restrict__ Pd,
                                                 float* __restrict__ asrc,
                                                 float* __restrict__ adst, int Nn) {
  if ((int)blockIdx.x >= eb) {
    __shared__ float ps[1024], pd[1024];
    int t = threadIdx.x;
    for (int i = t; i < 1024; i += 256) { ps[i] = Ps[i]; pd[i] = Pd[i]; }
    __syncthreads();
    int n = (blockIdx.x - eb) * 256 + t;
    if (n >= Nn) return;
    const float4* xr = (const float4*)&x[(size_t)n * 128];
    float as[8], ad[8];
#pragma unroll
    for (int h = 0; h < 8; h++) { as[h] = 0.f; ad[h] = 0.f; }
    for (int k4 = 0; k4 < 32; k4++) {
      float4 xv = xr[k4];
      float xs[4] = {xv.x, xv.y, xv.z, xv.w};
#pragma unroll
      for (int j = 0; j < 4; j++) {
        int k = k4 * 4 + j;
#pragma unroll
        for (int h = 0; h < 8; h++) {
          as[h] += xs[j] * ps[k * 8 + h];
          ad[h] += xs[j] * pd[k * 8 + h];
        }
      }
    }
#pragma unroll
    for (int h = 0; h < 8; h++) {
      asrc[n * 8 + h] = as[h];
      adst[n * 8 + h] = ad[h];
    }
    return;
  }
  int i = blockIdx.x * 256 + threadIdx.x;
  if (i >= Etot) return;
  int p = atomicAdd(&cursor[dst[i]], 1);
  psrc[p] = src[i];
}

// ---- layer-1 x-side aggregation. R13: 4 waves/block (one node each; breaks the
// 1-wave-workgroup occupancy cap seen at 50%) + DEPTH-2 batch pipeline (valid
// here: aggx is latency-bound per R12 PMC - VALU 29%, HBM 4%, occ 50% - unlike
// agg1/agg2 which were L3-BW bound and depth-insensitive). ----
__global__ __launch_bounds__(256) void aggx_k(const ushort_t* __restrict__ xb,
                                              const float* __restrict__ asrc,
                                              const float* __restrict__ adst,
                                              const int* __restrict__ offs,
                                              const int* __restrict__ psrc,
                                              ushort_t* __restrict__ sb, int Nn) {
  int n = blockIdx.x * 4 + (threadIdx.x >> 6);
  if (n >= Nn) return;
  int l = threadIdx.x & 63;
  int u_mine = l >> 3, h_mine = l & 7;
  float adn = adst[n * 8 + h_mine];
  int e0 = offs[n], e1 = offs[n + 1];
  int c0 = l * 2;                       // channels 2l, 2l+1

  float acc0[8], acc1[8], wsum[8];
#pragma unroll
  for (int h = 0; h < 8; h++) { acc0[h] = 0.f; acc1[h] = 0.f; wsum[h] = 0.f; }

  auto loadb = [&](int ib, int bs, unsigned xv[8], float& wm) {
    int eu = ib + (u_mine < bs ? u_mine : bs - 1);
    int se = psrc[eu];
    float v = asrc[se * 8 + h_mine] + adn;   // 8 nodes x 32B contiguous
    v = (v > 0.f) ? v : NEG * v;             // leaky_relu(0.2)
    wm = __expf(v);                          // hw v_exp_f32
    int ss[8];
#pragma unroll
    for (int u = 0; u < 8; u++) ss[u] = psrc[ib + (u < bs ? u : bs - 1)];
#pragma unroll
    for (int u = 0; u < 8; u++) xv[u] = *(const unsigned*)&xb[(size_t)ss[u] * 128 + c0];
  };

  int i = e0;
  unsigned xvA[8];
  float wmA = 0.f;
  int bsA = 0;
  if (i < e1) { bsA = min(8, e1 - i); loadb(i, bsA, xvA, wmA); }
  while (i < e1) {
    unsigned xvB[8];
    float wmB = 0.f;
    int bsB = 0;
    int inext = i + 8;
    if (inext < e1) { bsB = min(8, e1 - inext); loadb(inext, bsB, xvB, wmB); }
#pragma unroll
    for (int u = 0; u < 8; u++) {
      if (u < bsA) {
        union { unsigned u; float f; } a, b;
        a.u = xvA[u] << 16; b.u = xvA[u] & 0xffff0000u;
#pragma unroll
        for (int h = 0; h < 8; h++) {
          float w = __shfl(wmA, (u << 3) | h);
          acc0[h] += w * a.f;
          acc1[h] += w * b.f;
          wsum[h] += w;
        }
      }
    }
    i = inext;
    bsA = bsB;
    wmA = wmB;
#pragma unroll
    for (int u = 0; u < 8; u++) xvA[u] = xvB[u];
  }

#pragma unroll
  for (int h = 0; h < 8; h++) {
    float inv = 1.f / wsum[h];
    unsigned pr = (unsigned)f2bf(acc0[h] * inv) | ((unsigned)f2bf(acc1[h] * inv) << 16);
    *(unsigned*)&sb[(size_t)n * 1024 + h * 128 + c0] = pr;
  }
}

// ---- head-blocked GEMM: g1[n, h*128+j] = elu( s[n,h,:] . W1[:, h*128+j] + b1 ) ----
__global__ __launch_bounds__(256) void hgemm_k(const ushort_t* __restrict__ S,
                                               const ushort_t* __restrict__ Wt,
                                               const float* __restrict__ bias,
                                               ushort_t* __restrict__ G, int M) {
  __shared__ __attribute__((aligned(16))) ushort_t lds[32768];
  int tid = threadIdx.x;
  int lane = tid & 63;
  int wave = tid >> 6;
  int wm = (wave >> 1) * 64, wn = (wave & 1) * 64;
  int head = blockIdx.x;
  int hb0 = head * 128;
  int bm = blockIdx.y * 128;
  int lrow = lane & 15, lq = lane >> 4;

  f32x4 acc[4][4];
#pragma unroll
  for (int i = 0; i < 4; i++)
#pragma unroll
    for (int j = 0; j < 4; j++) acc[i][j] = 0.f;

  int srow = lane >> 3;
  int scol = 8 * ((lane & 7) ^ srow);
  const ushort_t* pa[4];
  const ushort_t* pb[4];
  int lofs[4];
#pragma unroll
  for (int c = 0; c < 4; c++) {
    int row = wave * 32 + c * 8 + srow;
    int ga = min(bm + row, M - 1);
    pa[c] = &S[(size_t)ga * 1024 + hb0 + scol];
    pb[c] = &Wt[(size_t)(hb0 + row) * 128 + scol];
    lofs[c] = (wave * 4 + c) * 512;
  }

  auto stage = [&](int buf, int k0) {
#pragma unroll
    for (int c = 0; c < 4; c++) GLDS16(pa[c] + k0, &lds[buf * 8192 + lofs[c]]);
#pragma unroll
    for (int c = 0; c < 4; c++) GLDS16(pb[c] + k0, &lds[16384 + buf * 8192 + lofs[c]]);
  };
  auto compute = [&](int buf) {
    const ushort_t* Asb = &lds[buf * 8192];
    const ushort_t* Bsb = &lds[16384 + buf * 8192];
#pragma unroll
    for (int ks = 0; ks < 2; ks++) {
      short8 af[4], bfr[4];
#pragma unroll
      for (int t = 0; t < 4; t++) {
        int cbs = (ks * 64 + lq * 16) ^ ((lrow & 7) << 4);
        af[t]  = *(const short8*)&Asb[(wm + t * 16 + lrow) * 64 + (cbs >> 1)];
        bfr[t] = *(const short8*)&Bsb[(wn + t * 16 + lrow) * 64 + (cbs >> 1)];
      }
#pragma unroll
      for (int i = 0; i < 4; i++)
#pragma unroll
        for (int j = 0; j < 4; j++)
          acc[i][j] = __builtin_amdgcn_mfma_f32_16x16x32_bf16(af[i], bfr[j], acc[i][j], 0, 0, 0);
    }
  };

  stage(0, 0);
  asm volatile("s_waitcnt vmcnt(0)" ::: "memory");
  __builtin_amdgcn_s_barrier();
  stage(1, 64);
  compute(0);
  asm volatile("s_waitcnt vmcnt(0)" ::: "memory");
  __builtin_amdgcn_s_barrier();
  compute(1);

  __syncthreads();

  ushort_t* Cl = lds;  // [128][136]
  float bv[4];
#pragma unroll
  for (int j = 0; j < 4; j++) bv[j] = bias[hb0 + wn + j * 16 + lrow];
#pragma unroll
  for (int i = 0; i < 4; i++) {
#pragma unroll
    for (int j = 0; j < 4; j++) {
      int col = wn + j * 16 + lrow;
#pragma unroll
      for (int r = 0; r < 4; r++) {
        int row = wm + i * 16 + lq * 4 + r;
        Cl[row * 136 + col] = f2bf(elu_f(acc[i][j][r] + bv[j]));
      }
    }
  }
  __syncthreads();
#pragma unroll
  for (int p = 0; p < 8; p++) {
    int row = p * 16 + (tid >> 4);
    int col8 = (tid & 15) * 8;
    if (bm + row < M)
      *(uint4*)&G[(size_t)(bm + row) * 1024 + hb0 + col8] = *(const uint4*)&Cl[row * 136 + col8];
  }
}

// ------- layer-2 GEMM, BN=64, dbuf GLDS pipeline, fixed epilogue -------
__global__ __launch_bounds__(256) void mfma_gemm_k(const ushort_t* __restrict__ A,
                                                   const ushort_t* __restrict__ Bt,
                                                   ushort_t* __restrict__ Cb,
                                                   const float* __restrict__ att_s,
                                                   const float* __restrict__ att_d,
                                                   float* __restrict__ asrc,
                                                   float* __restrict__ adst,
                                                   int M, int N, int K, int CSHIFT) {
  __shared__ __attribute__((aligned(16))) ushort_t lds[24576];  // 48KB multi-use
  int tid = threadIdx.x;
  int lane = tid & 63;
  int wave = tid >> 6;
  int wm = (wave >> 1) * 64, wn = (wave & 1) * 32;
  int bm = blockIdx.y * 128, bn = blockIdx.x * 64;
  int lrow = lane & 15, lq = lane >> 4;

  f32x4 acc[4][2];
#pragma unroll
  for (int i = 0; i < 4; i++)
#pragma unroll
    for (int j = 0; j < 2; j++) acc[i][j] = 0.f;

  int srow = lane >> 3;
  int scol = 8 * ((lane & 7) ^ srow);
  const ushort_t* pa[4];
  int laofs[4];
#pragma unroll
  for (int c = 0; c < 4; c++) {
    int row = wave * 32 + c * 8 + srow;
    int ga = min(bm + row, M - 1);
    pa[c] = &A[(size_t)ga * K + scol];
    laofs[c] = (wave * 4 + c) * 512;
  }
  const ushort_t* pb[2];
  int lbofs[2];
#pragma unroll
  for (int c = 0; c < 2; c++) {
    int row = wave * 16 + c * 8 + srow;
    pb[c] = &Bt[(size_t)(bn + row) * K + scol];
    lbofs[c] = (wave * 2 + c) * 512;
  }

  auto stage = [&](int buf, int k0) {
#pragma unroll
    for (int c = 0; c < 4; c++) GLDS16(pa[c] + k0, &lds[buf * 8192 + laofs[c]]);
#pragma unroll
    for (int c = 0; c < 2; c++) GLDS16(pb[c] + k0, &lds[16384 + buf * 4096 + lbofs[c]]);
  };
  auto compute = [&](int buf) {
    const ushort_t* Asb = &lds[buf * 8192];
    const ushort_t* Bsb = &lds[16384 + buf * 4096];
#pragma unroll
    for (int ks = 0; ks < 2; ks++) {
      int cbs = (ks * 64 + lq * 16) ^ ((lrow & 7) << 4);
      short8 af[4], bfr[2];
#pragma unroll
      for (int t = 0; t < 4; t++)
        af[t]  = *(const short8*)&Asb[(wm + t * 16 + lrow) * 64 + (cbs >> 1)];
#pragma unroll
      for (int t = 0; t < 2; t++)
        bfr[t] = *(const short8*)&Bsb[(wn + t * 16 + lrow) * 64 + (cbs >> 1)];
#pragma unroll
      for (int i = 0; i < 4; i++)
#pragma unroll
        for (int j = 0; j < 2; j++)
          acc[i][j] = __builtin_amdgcn_mfma_f32_16x16x32_bf16(af[i], bfr[j], acc[i][j], 0, 0, 0);
    }
  };

  int NT = K >> 6;
  stage(0, 0);
  asm volatile("s_waitcnt vmcnt(0)" ::: "memory");
  __builtin_amdgcn_s_barrier();
  int cur = 0;
  for (int t = 0; t + 1 < NT; ++t) {
    stage(cur ^ 1, (t + 1) << 6);
    compute(cur);
    asm volatile("s_waitcnt vmcnt(0)" ::: "memory");
    __builtin_amdgcn_s_barrier();
    cur ^= 1;
  }
  compute(cur);

  __syncthreads();  // done reading staging LDS -> safe to alias

  ushort_t* Cl = lds;                       // [128][72]
  float* pls = (float*)&lds[20480];
  float* pld = pls + 256;

  int hh = bn >> CSHIFT;
  {
    float avs[2], avd[2];
#pragma unroll
    for (int j = 0; j < 2; j++) {
      int col = bn + wn + j * 16 + lrow;
      avs[j] = att_s[col];
      avd[j] = att_d[col];
    }
#pragma unroll
    for (int i = 0; i < 4; i++) {
#pragma unroll
      for (int r = 0; r < 4; r++) {
        float ps = 0.f, pd = 0.f;
#pragma unroll
        for (int j = 0; j < 2; j++) {
          float v = acc[i][j][r];
          ps += v * avs[j];
          pd += v * avd[j];
        }
#pragma unroll
        for (int o = 1; o < 16; o <<= 1) {
          ps += __shfl_xor(ps, o);
          pd += __shfl_xor(pd, o);
        }
        if (lrow == 0) {
          int rr = i * 16 + lq * 4 + r;
          pls[wave * 64 + rr] = ps;
          pld[wave * 64 + rr] = pd;
        }
      }
    }
  }

#pragma unroll
  for (int i = 0; i < 4; i++) {
#pragma unroll
    for (int j = 0; j < 2; j++) {
      int col = wn + j * 16 + lrow;
#pragma unroll
      for (int r = 0; r < 4; r++) {
        int row = wm + i * 16 + lq * 4 + r;
        Cl[row * 72 + col] = f2bf(acc[i][j][r]);
      }
    }
  }
  __syncthreads();

#pragma unroll
  for (int p = 0; p < 4; p++) {
    int row = p * 32 + (tid >> 3);
    int col8 = (tid & 7) * 8;
    if (bm + row < M)
      *(uint4*)&Cb[(size_t)(bm + row) * N + bn + col8] = *(const uint4*)&Cl[row * 72 + col8];
  }

  {
    int r = tid & 127, half = tid >> 7;
    if (bm + r < M) {
      const float* P = half ? pld : pls;
      float* O = half ? adst : asrc;
      int w0 = (r >> 6) * 2, idx = r & 63;
      O[(size_t)(bm + r) * HEADS + hh] = P[w0 * 64 + idx] + P[(w0 + 1) * 64 + idx];
    }
  }
}

// ---- CSR aggregation (layer 2): depth-2 gathers + wave alpha sharing.
// R13: 4 units per 256-thread block (unit = 1 wave, was 1-wave workgroups). ----
template <int F, int CSHIFT, int BT, int NSPLIT, typename OT>
__global__ __launch_bounds__(256) void aggregate_k(const ushort_t* __restrict__ hb,
                                                   const float* __restrict__ asrc,
                                                   const float* __restrict__ adst,
                                                   const int* __restrict__ offs,
                                                   const int* __restrict__ psrc,
                                                   const float* __restrict__ bias,
                                                   OT* __restrict__ out, int NU) {
  constexpr int CPB = F / NSPLIT;
  constexpr int G = (1 << CSHIFT) >> 2;
  static_assert(CPB == 4 * BT, "CPB/thread mismatch");
  static_assert(BT == 64, "unit = one wave");
  static_assert(G >= 8 && G <= 64, "head group must cover the 8-edge batch");
  int unit = blockIdx.x * 4 + (threadIdx.x >> 6);
  if (unit >= NU) return;
  int n = unit / NSPLIT;
  int coff = (unit - n * NSPLIT) * CPB;
  int t = threadIdx.x & 63;
  int c0 = coff + 4 * t;
  int hh = c0 >> CSHIFT;
  int lane = t;
  int sub = lane & (G - 1);
  int gb = lane & ~(G - 1);
  float adn = adst[n * HEADS + hh];
  int e0 = offs[n], e1 = offs[n + 1];
  float4 acc = make_float4(0.f, 0.f, 0.f, 0.f);
  float wsum = 0.f;

  int i = e0;
  uint2 rA[8];
  float myWA = 0.f;
  bool haveA = (i + 8 <= e1);
  if (haveA) {
    int sA[8];
#pragma unroll
    for (int u = 0; u < 8; u++) sA[u] = psrc[i + u];
#pragma unroll
    for (int u = 0; u < 8; u++) rA[u] = *(const uint2*)&hb[(size_t)sA[u] * F + c0];
    int ms = psrc[i + (sub < 8 ? sub : 0)];
    float v = asrc[ms * HEADS + hh] + adn;
    v = (v > 0.f) ? v : NEG * v;
    myWA = __expf(v);
  }
  while (i + 16 <= e1) {
    int sB[8];
    uint2 rB[8];
#pragma unroll
    for (int u = 0; u < 8; u++) sB[u] = psrc[i + 8 + u];
#pragma unroll
    for (int u = 0; u < 8; u++) rB[u] = *(const uint2*)&hb[(size_t)sB[u] * F + c0];
    int ms = psrc[i + 8 + (sub < 8 ? sub : 0)];
    float vb = asrc[ms * HEADS + hh] + adn;
    vb = (vb > 0.f) ? vb : NEG * vb;
    float myWB = __expf(vb);
#pragma unroll
    for (int u = 0; u < 8; u++) {
      float w = __shfl(myWA, gb + u);
      float4 f = bf4(rA[u]);
      wsum += w;
      acc.x += w * f.x;
      acc.y += w * f.y;
      acc.z += w * f.z;
      acc.w += w * f.w;
    }
    i += 8;
#pragma unroll
    for (int u = 0; u < 8; u++) rA[u] = rB[u];
    myWA = myWB;
  }
  if (haveA) {
#pragma unroll
    for (int u = 0; u < 8; u++) {
      float w = __shfl(myWA, gb + u);
      float4 f = bf4(rA[u]);
      wsum += w;
      acc.x += w * f.x;
      acc.y += w * f.y;
      acc.z += w * f.z;
      acc.w += w * f.w;
    }
    i += 8;
  }
  for (; i < e1; i++) {
    int ss = psrc[i];
    float v = asrc[ss * HEADS + hh] + adn;
    v = (v > 0.f) ? v : NEG * v;
    float w = __expf(v);
    float4 f = bf4(*(const uint2*)&hb[(size_t)ss * F + c0]);
    wsum += w;
    acc.x += w * f.x; acc.y += w * f.y;
    acc.z += w * f.z; acc.w += w * f.w;
  }

  float inv = 1.f / wsum;
  float v0 = elu_f(acc.x * inv + bias[c0]);
  float v1 = elu_f(acc.y * inv + bias[c0 + 1]);
  float v2 = elu_f(acc.z * inv + bias[c0 + 2]);
  float v3 = elu_f(acc.w * inv + bias[c0 + 3]);
  if constexpr (sizeof(OT) == 2) {
    unsigned p0 = (unsigned)f2bf(v0) | ((unsigned)f2bf(v1) << 16);
    unsigned p1 = (unsigned)f2bf(v2) | ((unsigned)f2bf(v3) << 16);
    *(uint2*)&((ushort_t*)out)[(size_t)n * F + c0] = make_uint2(p0, p1);
  } else {
    *(float4*)&((float*)out)[(size_t)n * F + c0] = make_float4(v0, v1, v2, v3);
  }
}

__global__ __launch_bounds__(256) void pool_k(const float* __restrict__ g,
                                              const int* __restrict__ batch,
                                              float* __restrict__ sums, int Nn) {
  int c = blockIdx.x * 256 + threadIdx.x;  // 0..511
  int n0 = blockIdx.y * 50;
  int n1 = min(n0 + 50, Nn);
  if (n0 >= n1) return;
  float acc = 0.f;
  int cur = batch[n0];
  for (int n = n0; n < n1; n++) {
    int b = batch[n];
    if (b != cur) { atomicAdd(&sums[cur * 512 + c], acc); acc = 0.f; cur = b; }
    acc += g[(size_t)n * 512 + c];
  }
  atomicAdd(&sums[cur * 512 + c], acc);
}

// ---------------- mean + fc1(elu) + fc2, one block ----------------
__global__ __launch_bounds__(512) void mlp_k(const float* __restrict__ sums,
                                             const int* __restrict__ bstart,
                                             const int* __restrict__ bend,
                                             const float* __restrict__ w1,
                                             const float* __restrict__ b1,
                                             const float* __restrict__ w2,
                                             const float* __restrict__ b2,
                                             float* __restrict__ out) {
  __shared__ float gm[16 * 512];
  __shared__ float t1[16 * 32];
  int t = threadIdx.x;
  for (int i = t; i < 16 * 512; i += 512) {
    int b = i >> 9;
    float c = (float)(bend[b] - bstart[b]);
    gm[i] = sums[i] / fmaxf(c, 1.f);
  }
  __syncthreads();
  {
    int b = t >> 5, j = t & 31;
    float s = b1[j];
    for (int k = 0; k < 512; k++) s += gm[(b << 9) + k] * w1[k * 32 + j];
    t1[t] = elu_f(s);
  }
  __syncthreads();
  if (t < 160) {
    int b = t / 10, j = t - b * 10;
    float s = b2[j];
#pragma unroll
    for (int k = 0; k < 32; k++) s += t1[b * 32 + k] * w2[k * 10 + j];
    out[t] = s;
  }
}

extern "C" void kernel_launch(void* const* d_in, const int* in_sizes, int n_in,
                              void* d_out, int out_size, void* d_ws, size_t ws_size,
                              hipStream_t stream) {
  const float* x   = (const float*)d_in[0];
  const int*   ei  = (const int*)d_in[1];
  const int* batch = (const int*)d_in[2];
  const float* W1  = (const float*)d_in[3];
  const float* as1 = (const float*)d_in[4];
  const float* ad1 = (const float*)d_in[5];
  const float* b1  = (const float*)d_in[6];
  const float* W2  = (const float*)d_in[7];
  const float* as2 = (const float*)d_in[8];
  const float* ad2 = (const float*)d_in[9];
  const float* b2  = (const float*)d_in[10];
  const float* f1w = (const float*)d_in[11];
  const float* f1b = (const float*)d_in[12];
  const float* f2w = (const float*)d_in[13];
  const float* f2b = (const float*)d_in[14];
  float* out = (float*)d_out;

  const int Nn = in_sizes[2];      // 10000
  const int E = in_sizes[1] / 2;   // 160000
  const int Etot = E + Nn;         // self loops appended

  // ---- workspace layout (4B words, 64-word aligned) ----
  size_t off = 0;
  auto alloc = [&](size_t elems) { size_t o = off; off += (elems + 63) & ~(size_t)63; return o; };
  int* wsi = (int*)d_ws;
  float* wsf = (float*)d_ws;

  size_t o_deg  = alloc(Nn);
  size_t o_pool = alloc(16 * 512);
  size_t zero_words = off;               // only deg+pool accumulate -> zero each call
  size_t o_as1  = alloc((size_t)Nn * 8);
  size_t o_ad1  = alloc((size_t)Nn * 8);
  size_t o_as2  = alloc((size_t)Nn * 8);
  size_t o_ad2  = alloc((size_t)Nn * 8);
  size_t o_ps   = alloc(1024);           // P projections [128][8] fp32
  size_t o_pd   = alloc(1024);
  size_t o_bst  = alloc(64);
  size_t o_ben  = alloc(64);
  size_t o_offs = alloc(Nn + 1);
  size_t o_cur  = alloc(Nn);
  size_t o_src  = alloc(Etot);
  size_t o_dst  = alloc(Etot);
  size_t o_psrc = alloc(Etot);
  size_t o_xb   = alloc((size_t)Nn * 128 / 2);   // x bf16  [N,128]
  size_t o_w1t  = alloc(1024 * 128 / 2);         // W1^T bf16 [1024,128]
  size_t o_w2t  = alloc(512 * 1024 / 2);         // W2^T bf16 [512,1024]
  size_t o_s    = alloc((size_t)Nn * 1024 / 2);  // s bf16 [N,1024]
  size_t o_h    = alloc((size_t)Nn * 1024 / 2);  // h2 bf16 [N,512] (first half)
  size_t o_g    = alloc((size_t)Nn * 1024);      // g1 bf16 (first half) then g2 fp32

  ushort_t* xb  = (ushort_t*)(wsi + o_xb);
  ushort_t* w1t = (ushort_t*)(wsi + o_w1t);
  ushort_t* w2t = (ushort_t*)(wsi + o_w2t);
  ushort_t* sb  = (ushort_t*)(wsi + o_s);
  ushort_t* hb  = (ushort_t*)(wsi + o_h);
  ushort_t* g1b = (ushort_t*)(wsi + o_g);

  int eb = (Etot + 255) / 256;
  int ab = (Nn + 255) / 256;  // al1 tail blocks on scatter grid

  int nx4 = Nn * 128 / 4;
  int ep_work = (int)((zero_words > (size_t)nx4 ? zero_words : (size_t)nx4));
  int init_blocks = 648 + (ep_work + 255) / 256;
  init_k<<<init_blocks, 256, 0, stream>>>(wsi, (int)zero_words, x, xb,
                                          W1, w1t, W2, w2t,
                                          as1, ad1, wsf + o_ps, wsf + o_pd, nx4);
  prep_k<<<eb, 256, 0, stream>>>(ei, wsi + o_src, wsi + o_dst, wsi + o_deg,
                                 batch, wsi + o_bst, wsi + o_ben, E, Nn);
  scan_k<<<1, 1024, 0, stream>>>(wsi + o_deg, wsi + o_offs, wsi + o_cur, Nn);
  scatter_k<<<eb + ab, 256, 0, stream>>>(wsi + o_src, wsi + o_dst, wsi + o_cur,
                                         wsi + o_psrc, Etot, eb,
                                         x, wsf + o_ps, wsf + o_pd,
                                         wsf + o_as1, wsf + o_ad1, Nn);

  // ---- layer 1 (restructured): aggregate x; head-blocked GEMM ----
  aggx_k<<<(Nn + 3) / 4, 256, 0, stream>>>(xb, wsf + o_as1, wsf + o_ad1,
                                           wsi + o_offs, wsi + o_psrc, sb, Nn);
  hgemm_k<<<dim3(8, (Nn + 127) / 128), 256, 0, stream>>>(sb, w1t, b1, g1b, Nn);

  // ---- layer 2: 1024 -> 8x64 (BN=64 tile) ----
  mfma_gemm_k<<<dim3(512 / 64, (Nn + 127) / 128), 256, 0, stream>>>(
      g1b, w2t, hb, as2, ad2, wsf + o_as2, wsf + o_ad2, Nn, 512, 1024, 6);
  aggregate_k<512, 6, 64, 2, float><<<(Nn * 2 + 3) / 4, 256, 0, stream>>>(
      hb, wsf + o_as2, wsf + o_ad2, wsi + o_offs, wsi + o_psrc, b2, wsf + o_g, Nn * 2);

  // ---- pool + MLP ----
  pool_k<<<dim3(2, (Nn + 49) / 50), 256, 0, stream>>>(wsf + o_g, batch, wsf + o_pool, Nn);
  mlp_k<<<1, 512, 0, stream>>>(wsf + o_pool, wsi + o_bst, wsi + o_ben, f1w, f1b, f2w, f2b, out);
}

// Round 14
// 257.373 us; speedup vs baseline: 1.6021x; 1.0170x over previous
//
#include <hip/hip_runtime.h>
#include <math.h>

#define HEADS 8
#define NEG 0.2f

typedef unsigned short ushort_t;
typedef __attribute__((ext_vector_type(8))) short short8;
typedef float f32x4 __attribute__((ext_vector_type(4)));

__device__ inline ushort_t f2bf(float f) {
  union { float f; unsigned u; } v; v.f = f;
  unsigned r = (v.u + 0x7FFF + ((v.u >> 16) & 1)) >> 16;  // RNE
  return (ushort_t)r;
}

__device__ inline float4 bf4(uint2 v) {
  union { unsigned u; float f; } a, b, c, d;
  a.u = v.x << 16; b.u = v.x & 0xffff0000u;
  c.u = v.y << 16; d.u = v.y & 0xffff0000u;
  return make_float4(a.f, b.f, c.f, d.f);
}

// fast ELU: exp(v)-1 via hw v_exp_f32; |abs err| ~1e-7, fine vs 1.7e-3 threshold
__device__ inline float elu_f(float v) {
  return (v > 0.f) ? v : (__expf(v) - 1.f);
}

// async global->LDS, 16B per lane; LDS dest is wave-uniform base + lane*16
#define GLDS16(gp, lp)                                                          \
  __builtin_amdgcn_global_load_lds(                                             \
      (const __attribute__((address_space(1))) void*)(gp),                      \
      (__attribute__((address_space(3))) void*)(lp), 16, 0, 0)

// ---- fused init: W transposes + P projection + zero + x->bf16 ----
__global__ __launch_bounds__(256) void init_k(int* __restrict__ ws, int zero_words,
                                              const float* __restrict__ x,
                                              ushort_t* __restrict__ xb,
                                              const float* __restrict__ W1,
                                              ushort_t* __restrict__ w1t,
                                              const float* __restrict__ W2,
                                              ushort_t* __restrict__ w2t,
                                              const float* __restrict__ as1,
                                              const float* __restrict__ ad1,
                                              float* __restrict__ Ps,
                                              float* __restrict__ Pd, int nx4) {
  __shared__ float tile[32][33];
  int blk = blockIdx.x;
  if (blk < 640) {
    const float* W; ushort_t* Wt; int K, N, tk, tn;
    if (blk < 128) { W = W1; Wt = w1t; K = 128; N = 1024; tk = blk >> 5; tn = blk & 31; }
    else { W = W2; Wt = w2t; K = 1024; N = 512; int t = blk - 128; tk = t >> 4; tn = t & 15; }
    int tx = threadIdx.x & 31, ty = threadIdx.x >> 5;  // 32 x 8
    int k0 = tk * 32, n0 = tn * 32;
#pragma unroll
    for (int r = 0; r < 4; r++)
      tile[ty + r * 8][tx] = W[(size_t)(k0 + ty + r * 8) * N + n0 + tx];  // coalesced read
    __syncthreads();
#pragma unroll
    for (int r = 0; r < 4; r++)
      Wt[(size_t)(n0 + ty + r * 8) * K + k0 + tx] = f2bf(tile[tx][ty + r * 8]);  // coalesced write
  } else if (blk < 648) {
    int h = blk - 640;
    int t = threadIdx.x;
    int k = t >> 1, sd = t & 1;
    const float* att = sd ? ad1 : as1;
    float* P = sd ? Pd : Ps;
    const float* wrow = &W1[(size_t)k * 1024 + h * 128];
    const float* arow = &att[h * 128];
    float s = 0.f;
#pragma unroll 8
    for (int c = 0; c < 128; c++) s += wrow[c] * arow[c];
    P[k * 8 + h] = s;
  } else {
    int i = (blk - 648) * 256 + threadIdx.x;
    if (i < zero_words) ws[i] = 0;
    if (i < nx4) {
      float4 v = ((const float4*)x)[i];
      ushort_t o[4] = {f2bf(v.x), f2bf(v.y), f2bf(v.z), f2bf(v.w)};
      *(uint2*)&xb[i * 4] = *(uint2*)o;
    }
  }
}

// -- edge prep + degree count + batch bounds fused (batch sorted; no atomics) --
__global__ void prep_k(const int* __restrict__ ei, int* __restrict__ src,
                       int* __restrict__ dst, int* __restrict__ deg,
                       const int* __restrict__ batch, int* __restrict__ bstart,
                       int* __restrict__ bend, int E, int Nn) {
  int i = blockIdx.x * blockDim.x + threadIdx.x;
  if (i < Nn) {
    int b = batch[i];
    if (i == 0 || batch[i - 1] != b) bstart[b] = i;
    if (i == Nn - 1 || batch[i + 1] != b) bend[b] = i + 1;
  }
  if (i >= E + Nn) return;
  int s, d;
  if (i < E) { s = ei[i]; d = ei[E + i]; }
  else       { s = d = i - E; }
  src[i] = s;
  dst[i] = d;
  atomicAdd(&deg[d], 1);
}

// single-block scan over N, 4 elems/thread (4096/chunk), wave-shuffle based
__global__ __launch_bounds__(1024) void scan_k(const int* __restrict__ deg,
                                               int* __restrict__ offs,
                                               int* __restrict__ cursor, int Nn) {
  __shared__ int wtot[16];
  __shared__ int wexcl[16];
  __shared__ int soff_s;
  int t = threadIdx.x;
  int lane = t & 63, w = t >> 6;
  if (t == 0) soff_s = 0;
  __syncthreads();
  for (int base = 0; base < Nn; base += 4096) {
    int idx = base + 4 * t;
    int4 v = make_int4(0, 0, 0, 0);
    if (idx + 3 < Nn) v = *(const int4*)&deg[idx];
    else {
      if (idx < Nn)     v.x = deg[idx];
      if (idx + 1 < Nn) v.y = deg[idx + 1];
      if (idx + 2 < Nn) v.z = deg[idx + 2];
      if (idx + 3 < Nn) v.w = deg[idx + 3];
    }
    int s1 = v.x, s2 = s1 + v.y, s3 = s2 + v.z, s4 = s3 + v.w;
    int sc = s4;  // wave-inclusive scan of per-thread totals
#pragma unroll
    for (int o = 1; o < 64; o <<= 1) {
      int x = __shfl_up(sc, o);
      if (lane >= o) sc += x;
    }
    if (lane == 63) wtot[w] = sc;
    __syncthreads();
    if (w == 0) {
      int tv = (lane < 16) ? wtot[lane] : 0;
      int ts = tv;
#pragma unroll
      for (int o = 1; o < 16; o <<= 1) {
        int x = __shfl_up(ts, o);
        if (lane >= o) ts += x;
      }
      if (lane < 16) wexcl[lane] = ts - tv;
      if (lane == 15) wtot[15] = ts;  // chunk total
    }
    __syncthreads();
    int excl = soff_s + wexcl[w] + (sc - s4);
    int o0 = excl, o1 = excl + s1, o2 = excl + s2, o3 = excl + s3;
    if (idx < Nn)     { offs[idx] = o0;     cursor[idx] = o0; }
    if (idx + 1 < Nn) { offs[idx + 1] = o1; cursor[idx + 1] = o1; }
    if (idx + 2 < Nn) { offs[idx + 2] = o2; cursor[idx + 2] = o2; }
    if (idx + 3 < Nn) { offs[idx + 3] = o3; cursor[idx + 3] = o3; }
    int chunk_total = wtot[15];
    __syncthreads();
    if (t == 0) soff_s += chunk_total;
    __syncthreads();
  }
  if (t == 0) offs[Nn] = soff_s;
}

// scatter src into CSR slot order; tail blocks (>= eb) run the layer-1 alpha GEMV
__global__ __launch_bounds__(256) void scatter_k(const int* __restrict__ src,
                                                 const int* __restrict__ dst,
                                                 int* __restrict__ cursor,
                                                 int* __restrict__ psrc, int Etot, int eb,
                                                 const float* __restrict__ x,
                                                 const float* __restrict__ Ps,
                                                 const float* __restrict__ Pd,
                                                 float* __restrict__ asrc,
                                                 float* __restrict__ adst, int Nn) {
  if ((int)blockIdx.x >= eb) {
    __shared__ float ps[1024], pd[1024];
    int t = threadIdx.x;
    for (int i = t; i < 1024; i += 256) { ps[i] = Ps[i]; pd[i] = Pd[i]; }
    __syncthreads();
    int n = (blockIdx.x - eb) * 256 + t;
    if (n >= Nn) return;
    const float4* xr = (const float4*)&x[(size_t)n * 128];
    float as[8], ad[8];
#pragma unroll
    for (int h = 0; h < 8; h++) { as[h] = 0.f; ad[h] = 0.f; }
    for (int k4 = 0; k4 < 32; k4++) {
      float4 xv = xr[k4];
      float xs[4] = {xv.x, xv.y, xv.z, xv.w};
#pragma unroll
      for (int j = 0; j < 4; j++) {
        int k = k4 * 4 + j;
#pragma unroll
        for (int h = 0; h < 8; h++) {
          as[h] += xs[j] * ps[k * 8 + h];
          ad[h] += xs[j] * pd[k * 8 + h];
        }
      }
    }
#pragma unroll
    for (int h = 0; h < 8; h++) {
      asrc[n * 8 + h] = as[h];
      adst[n * 8 + h] = ad[h];
    }
    return;
  }
  int i = blockIdx.x * 256 + threadIdx.x;
  if (i >= Etot) return;
  int p = atomicAdd(&cursor[dst[i]], 1);
  psrc[p] = src[i];
}

// ---- layer-1 x-side aggregation. R14: 2 waves/block (one node each) — SINGLE
// variable change vs R11's 1-wave blocks. R12 PMC showed occupancy pinned at
// 50% = the 16-workgroup/CU slot limit with 64-thread groups; 128-thread groups
// raise the ceiling to 32 waves/CU. Inner loop byte-identical to R11 (R13's
// depth-2+4-wave conflated two variables and regressed). ----
__global__ __launch_bounds__(128) void aggx_k(const ushort_t* __restrict__ xb,
                                              const float* __restrict__ asrc,
                                              const float* __restrict__ adst,
                                              const int* __restrict__ offs,
                                              const int* __restrict__ psrc,
                                              ushort_t* __restrict__ sb, int Nn) {
  int n = blockIdx.x * 2 + (threadIdx.x >> 6);
  if (n >= Nn) return;
  int l = threadIdx.x & 63;
  int u_mine = l >> 3, h_mine = l & 7;
  float adn = adst[n * 8 + h_mine];
  int e0 = offs[n], e1 = offs[n + 1];
  int c0 = l * 2;                       // channels 2l, 2l+1
  float acc0[8], acc1[8], wsum[8];
#pragma unroll
  for (int h = 0; h < 8; h++) { acc0[h] = 0.f; acc1[h] = 0.f; wsum[h] = 0.f; }

  for (int i = e0; i < e1; i += 8) {
    int bs = min(8, e1 - i);
    int eu = i + (u_mine < bs ? u_mine : bs - 1);
    int se = psrc[eu];
    float v = asrc[se * 8 + h_mine] + adn;   // 8 nodes x 32B contiguous
    v = (v > 0.f) ? v : NEG * v;             // leaky_relu(0.2)
    float wm = __expf(v);                    // hw v_exp_f32
    int ss[8];
    unsigned xvv[8];
#pragma unroll
    for (int u = 0; u < 8; u++) ss[u] = psrc[i + (u < bs ? u : bs - 1)];
#pragma unroll
    for (int u = 0; u < 8; u++) xvv[u] = *(const unsigned*)&xb[(size_t)ss[u] * 128 + c0];
#pragma unroll
    for (int u = 0; u < 8; u++) {
      if (u < bs) {
        union { unsigned u; float f; } a, b;
        a.u = xvv[u] << 16; b.u = xvv[u] & 0xffff0000u;
#pragma unroll
        for (int h = 0; h < 8; h++) {
          float w = __shfl(wm, ((u << 3) | h) | (threadIdx.x & 64));
          acc0[h] += w * a.f;
          acc1[h] += w * b.f;
          wsum[h] += w;
        }
      }
    }
  }

#pragma unroll
  for (int h = 0; h < 8; h++) {
    float inv = 1.f / wsum[h];
    unsigned pr = (unsigned)f2bf(acc0[h] * inv) | ((unsigned)f2bf(acc1[h] * inv) << 16);
    *(unsigned*)&sb[(size_t)n * 1024 + h * 128 + c0] = pr;
  }
}

// ---- head-blocked GEMM: g1[n, h*128+j] = elu( s[n,h,:] . W1[:, h*128+j] + b1 ) ----
__global__ __launch_bounds__(256) void hgemm_k(const ushort_t* __restrict__ S,
                                               const ushort_t* __restrict__ Wt,
                                               const float* __restrict__ bias,
                                               ushort_t* __restrict__ G, int M) {
  __shared__ __attribute__((aligned(16))) ushort_t lds[32768];
  int tid = threadIdx.x;
  int lane = tid & 63;
  int wave = tid >> 6;
  int wm = (wave >> 1) * 64, wn = (wave & 1) * 64;
  int head = blockIdx.x;
  int hb0 = head * 128;
  int bm = blockIdx.y * 128;
  int lrow = lane & 15, lq = lane >> 4;

  f32x4 acc[4][4];
#pragma unroll
  for (int i = 0; i < 4; i++)
#pragma unroll
    for (int j = 0; j < 4; j++) acc[i][j] = 0.f;

  int srow = lane >> 3;
  int scol = 8 * ((lane & 7) ^ srow);
  const ushort_t* pa[4];
  const ushort_t* pb[4];
  int lofs[4];
#pragma unroll
  for (int c = 0; c < 4; c++) {
    int row = wave * 32 + c * 8 + srow;
    int ga = min(bm + row, M - 1);
    pa[c] = &S[(size_t)ga * 1024 + hb0 + scol];
    pb[c] = &Wt[(size_t)(hb0 + row) * 128 + scol];
    lofs[c] = (wave * 4 + c) * 512;
  }

  auto stage = [&](int buf, int k0) {
#pragma unroll
    for (int c = 0; c < 4; c++) GLDS16(pa[c] + k0, &lds[buf * 8192 + lofs[c]]);
#pragma unroll
    for (int c = 0; c < 4; c++) GLDS16(pb[c] + k0, &lds[16384 + buf * 8192 + lofs[c]]);
  };
  auto compute = [&](int buf) {
    const ushort_t* Asb = &lds[buf * 8192];
    const ushort_t* Bsb = &lds[16384 + buf * 8192];
#pragma unroll
    for (int ks = 0; ks < 2; ks++) {
      short8 af[4], bfr[4];
#pragma unroll
      for (int t = 0; t < 4; t++) {
        int cbs = (ks * 64 + lq * 16) ^ ((lrow & 7) << 4);
        af[t]  = *(const short8*)&Asb[(wm + t * 16 + lrow) * 64 + (cbs >> 1)];
        bfr[t] = *(const short8*)&Bsb[(wn + t * 16 + lrow) * 64 + (cbs >> 1)];
      }
#pragma unroll
      for (int i = 0; i < 4; i++)
#pragma unroll
        for (int j = 0; j < 4; j++)
          acc[i][j] = __builtin_amdgcn_mfma_f32_16x16x32_bf16(af[i], bfr[j], acc[i][j], 0, 0, 0);
    }
  };

  stage(0, 0);
  asm volatile("s_waitcnt vmcnt(0)" ::: "memory");
  __builtin_amdgcn_s_barrier();
  stage(1, 64);
  compute(0);
  asm volatile("s_waitcnt vmcnt(0)" ::: "memory");
  __builtin_amdgcn_s_barrier();
  compute(1);

  __syncthreads();

  ushort_t* Cl = lds;  // [128][136]
  float bv[4];
#pragma unroll
  for (int j = 0; j < 4; j++) bv[j] = bias[hb0 + wn + j * 16 + lrow];
#pragma unroll
  for (int i = 0; i < 4; i++) {
#pragma unroll
    for (int j = 0; j < 4; j++) {
      int col = wn + j * 16 + lrow;
#pragma unroll
      for (int r = 0; r < 4; r++) {
        int row = wm + i * 16 + lq * 4 + r;
        Cl[row * 136 + col] = f2bf(elu_f(acc[i][j][r] + bv[j]));
      }
    }
  }
  __syncthreads();
#pragma unroll
  for (int p = 0; p < 8; p++) {
    int row = p * 16 + (tid >> 4);
    int col8 = (tid & 15) * 8;
    if (bm + row < M)
      *(uint4*)&G[(size_t)(bm + row) * 1024 + hb0 + col8] = *(const uint4*)&Cl[row * 136 + col8];
  }
}

// ------- layer-2 GEMM, BN=64, dbuf GLDS pipeline, fixed epilogue -------
__global__ __launch_bounds__(256) void mfma_gemm_k(const ushort_t* __restrict__ A,
                                                   const ushort_t* __restrict__ Bt,
                                                   ushort_t* __restrict__ Cb,
                                                   const float* __restrict__ att_s,
                                                   const float* __restrict__ att_d,
                                                   float* __restrict__ asrc,
                                                   float* __restrict__ adst,
                                                   int M, int N, int K, int CSHIFT) {
  __shared__ __attribute__((aligned(16))) ushort_t lds[24576];  // 48KB multi-use
  int tid = threadIdx.x;
  int lane = tid & 63;
  int wave = tid >> 6;
  int wm = (wave >> 1) * 64, wn = (wave & 1) * 32;
  int bm = blockIdx.y * 128, bn = blockIdx.x * 64;
  int lrow = lane & 15, lq = lane >> 4;

  f32x4 acc[4][2];
#pragma unroll
  for (int i = 0; i < 4; i++)
#pragma unroll
    for (int j = 0; j < 2; j++) acc[i][j] = 0.f;

  int srow = lane >> 3;
  int scol = 8 * ((lane & 7) ^ srow);
  const ushort_t* pa[4];
  int laofs[4];
#pragma unroll
  for (int c = 0; c < 4; c++) {
    int row = wave * 32 + c * 8 + srow;
    int ga = min(bm + row, M - 1);
    pa[c] = &A[(size_t)ga * K + scol];
    laofs[c] = (wave * 4 + c) * 512;
  }
  const ushort_t* pb[2];
  int lbofs[2];
#pragma unroll
  for (int c = 0; c < 2; c++) {
    int row = wave * 16 + c * 8 + srow;
    pb[c] = &Bt[(size_t)(bn + row) * K + scol];
    lbofs[c] = (wave * 2 + c) * 512;
  }

  auto stage = [&](int buf, int k0) {
#pragma unroll
    for (int c = 0; c < 4; c++) GLDS16(pa[c] + k0, &lds[buf * 8192 + laofs[c]]);
#pragma unroll
    for (int c = 0; c < 2; c++) GLDS16(pb[c] + k0, &lds[16384 + buf * 4096 + lbofs[c]]);
  };
  auto compute = [&](int buf) {
    const ushort_t* Asb = &lds[buf * 8192];
    const ushort_t* Bsb = &lds[16384 + buf * 4096];
#pragma unroll
    for (int ks = 0; ks < 2; ks++) {
      int cbs = (ks * 64 + lq * 16) ^ ((lrow & 7) << 4);
      short8 af[4], bfr[2];
#pragma unroll
      for (int t = 0; t < 4; t++)
        af[t]  = *(const short8*)&Asb[(wm + t * 16 + lrow) * 64 + (cbs >> 1)];
#pragma unroll
      for (int t = 0; t < 2; t++)
        bfr[t] = *(const short8*)&Bsb[(wn + t * 16 + lrow) * 64 + (cbs >> 1)];
#pragma unroll
      for (int i = 0; i < 4; i++)
#pragma unroll
        for (int j = 0; j < 2; j++)
          acc[i][j] = __builtin_amdgcn_mfma_f32_16x16x32_bf16(af[i], bfr[j], acc[i][j], 0, 0, 0);
    }
  };

  int NT = K >> 6;
  stage(0, 0);
  asm volatile("s_waitcnt vmcnt(0)" ::: "memory");
  __builtin_amdgcn_s_barrier();
  int cur = 0;
  for (int t = 0; t + 1 < NT; ++t) {
    stage(cur ^ 1, (t + 1) << 6);
    compute(cur);
    asm volatile("s_waitcnt vmcnt(0)" ::: "memory");
    __builtin_amdgcn_s_barrier();
    cur ^= 1;
  }
  compute(cur);

  __syncthreads();  // done reading staging LDS -> safe to alias

  ushort_t* Cl = lds;                       // [128][72]
  float* pls = (float*)&lds[20480];
  float* pld = pls + 256;

  int hh = bn >> CSHIFT;
  {
    float avs[2], avd[2];
#pragma unroll
    for (int j = 0; j < 2; j++) {
      int col = bn + wn + j * 16 + lrow;
      avs[j] = att_s[col];
      avd[j] = att_d[col];
    }
#pragma unroll
    for (int i = 0; i < 4; i++) {
#pragma unroll
      for (int r = 0; r < 4; r++) {
        float ps = 0.f, pd = 0.f;
#pragma unroll
        for (int j = 0; j < 2; j++) {
          float v = acc[i][j][r];
          ps += v * avs[j];
          pd += v * avd[j];
        }
#pragma unroll
        for (int o = 1; o < 16; o <<= 1) {
          ps += __shfl_xor(ps, o);
          pd += __shfl_xor(pd, o);
        }
        if (lrow == 0) {
          int rr = i * 16 + lq * 4 + r;
          pls[wave * 64 + rr] = ps;
          pld[wave * 64 + rr] = pd;
        }
      }
    }
  }

#pragma unroll
  for (int i = 0; i < 4; i++) {
#pragma unroll
    for (int j = 0; j < 2; j++) {
      int col = wn + j * 16 + lrow;
#pragma unroll
      for (int r = 0; r < 4; r++) {
        int row = wm + i * 16 + lq * 4 + r;
        Cl[row * 72 + col] = f2bf(acc[i][j][r]);
      }
    }
  }
  __syncthreads();

#pragma unroll
  for (int p = 0; p < 4; p++) {
    int row = p * 32 + (tid >> 3);
    int col8 = (tid & 7) * 8;
    if (bm + row < M)
      *(uint4*)&Cb[(size_t)(bm + row) * N + bn + col8] = *(const uint4*)&Cl[row * 72 + col8];
  }

  {
    int r = tid & 127, half = tid >> 7;
    if (bm + r < M) {
      const float* P = half ? pld : pls;
      float* O = half ? adst : asrc;
      int w0 = (r >> 6) * 2, idx = r & 63;
      O[(size_t)(bm + r) * HEADS + hh] = P[w0 * 64 + idx] + P[(w0 + 1) * 64 + idx];
    }
  }
}

// ---- CSR aggregation (layer 2): R11 inner loop (depth-2 + wave alpha sharing),
// R14: 2 units per 128-thread block (wg-slot occupancy fix, single variable). ----
template <int F, int CSHIFT, int BT, int NSPLIT, typename OT>
__global__ __launch_bounds__(128) void aggregate_k(const ushort_t* __restrict__ hb,
                                                   const float* __restrict__ asrc,
                                                   const float* __restrict__ adst,
                                                   const int* __restrict__ offs,
                                                   const int* __restrict__ psrc,
                                                   const float* __restrict__ bias,
                                                   OT* __restrict__ out, int NU) {
  constexpr int CPB = F / NSPLIT;
  constexpr int G = (1 << CSHIFT) >> 2;
  static_assert(CPB == 4 * BT, "CPB/thread mismatch");
  static_assert(BT == 64, "unit = one wave");
  static_assert(G >= 8 && G <= 64, "head group must cover the 8-edge batch");
  int unit = blockIdx.x * 2 + (threadIdx.x >> 6);
  if (unit >= NU) return;
  int n = unit / NSPLIT;
  int coff = (unit - n * NSPLIT) * CPB;
  int t = threadIdx.x & 63;
  int c0 = coff + 4 * t;
  int hh = c0 >> CSHIFT;
  int lane = t;
  int sub = lane & (G - 1);
  int gb = (lane & ~(G - 1)) | (threadIdx.x & 64);  // shfl src within own wave
  float adn = adst[n * HEADS + hh];
  int e0 = offs[n], e1 = offs[n + 1];
  float4 acc = make_float4(0.f, 0.f, 0.f, 0.f);
  float wsum = 0.f;

  int i = e0;
  uint2 rA[8];
  float myWA = 0.f;
  bool haveA = (i + 8 <= e1);
  if (haveA) {
    int sA[8];
#pragma unroll
    for (int u = 0; u < 8; u++) sA[u] = psrc[i + u];
#pragma unroll
    for (int u = 0; u < 8; u++) rA[u] = *(const uint2*)&hb[(size_t)sA[u] * F + c0];
    int ms = psrc[i + (sub < 8 ? sub : 0)];
    float v = asrc[ms * HEADS + hh] + adn;
    v = (v > 0.f) ? v : NEG * v;
    myWA = __expf(v);
  }
  while (i + 16 <= e1) {
    int sB[8];
    uint2 rB[8];
#pragma unroll
    for (int u = 0; u < 8; u++) sB[u] = psrc[i + 8 + u];
#pragma unroll
    for (int u = 0; u < 8; u++) rB[u] = *(const uint2*)&hb[(size_t)sB[u] * F + c0];
    int ms = psrc[i + 8 + (sub < 8 ? sub : 0)];
    float vb = asrc[ms * HEADS + hh] + adn;
    vb = (vb > 0.f) ? vb : NEG * vb;
    float myWB = __expf(vb);
#pragma unroll
    for (int u = 0; u < 8; u++) {
      float w = __shfl(myWA, gb + u);
      float4 f = bf4(rA[u]);
      wsum += w;
      acc.x += w * f.x;
      acc.y += w * f.y;
      acc.z += w * f.z;
      acc.w += w * f.w;
    }
    i += 8;
#pragma unroll
    for (int u = 0; u < 8; u++) rA[u] = rB[u];
    myWA = myWB;
  }
  if (haveA) {
#pragma unroll
    for (int u = 0; u < 8; u++) {
      float w = __shfl(myWA, gb + u);
      float4 f = bf4(rA[u]);
      wsum += w;
      acc.x += w * f.x;
      acc.y += w * f.y;
      acc.z += w * f.z;
      acc.w += w * f.w;
    }
    i += 8;
  }
  for (; i < e1; i++) {
    int ss = psrc[i];
    float v = asrc[ss * HEADS + hh] + adn;
    v = (v > 0.f) ? v : NEG * v;
    float w = __expf(v);
    float4 f = bf4(*(const uint2*)&hb[(size_t)ss * F + c0]);
    wsum += w;
    acc.x += w * f.x; acc.y += w * f.y;
    acc.z += w * f.z; acc.w += w * f.w;
  }

  float inv = 1.f / wsum;
  float v0 = elu_f(acc.x * inv + bias[c0]);
  float v1 = elu_f(acc.y * inv + bias[c0 + 1]);
  float v2 = elu_f(acc.z * inv + bias[c0 + 2]);
  float v3 = elu_f(acc.w * inv + bias[c0 + 3]);
  if constexpr (sizeof(OT) == 2) {
    unsigned p0 = (unsigned)f2bf(v0) | ((unsigned)f2bf(v1) << 16);
    unsigned p1 = (unsigned)f2bf(v2) | ((unsigned)f2bf(v3) << 16);
    *(uint2*)&((ushort_t*)out)[(size_t)n * F + c0] = make_uint2(p0, p1);
  } else {
    *(float4*)&((float*)out)[(size_t)n * F + c0] = make_float4(v0, v1, v2, v3);
  }
}

__global__ __launch_bounds__(256) void pool_k(const float* __restrict__ g,
                                              const int* __restrict__ batch,
                                              float* __restrict__ sums, int Nn) {
  int c = blockIdx.x * 256 + threadIdx.x;  // 0..511
  int n0 = blockIdx.y * 50;
  int n1 = min(n0 + 50, Nn);
  if (n0 >= n1) return;
  float acc = 0.f;
  int cur = batch[n0];
  for (int n = n0; n < n1; n++) {
    int b = batch[n];
    if (b != cur) { atomicAdd(&sums[cur * 512 + c], acc); acc = 0.f; cur = b; }
    acc += g[(size_t)n * 512 + c];
  }
  atomicAdd(&sums[cur * 512 + c], acc);
}

// ---------------- mean + fc1(elu) + fc2, one block ----------------
__global__ __launch_bounds__(512) void mlp_k(const float* __restrict__ sums,
                                             const int* __restrict__ bstart,
                                             const int* __restrict__ bend,
                                             const float* __restrict__ w1,
                                             const float* __restrict__ b1,
                                             const float* __restrict__ w2,
                                             const float* __restrict__ b2,
                                             float* __restrict__ out) {
  __shared__ float gm[16 * 512];
  __shared__ float t1[16 * 32];
  int t = threadIdx.x;
  for (int i = t; i < 16 * 512; i += 512) {
    int b = i >> 9;
    float c = (float)(bend[b] - bstart[b]);
    gm[i] = sums[i] / fmaxf(c, 1.f);
  }
  __syncthreads();
  {
    int b = t >> 5, j = t & 31;
    float s = b1[j];
    for (int k = 0; k < 512; k++) s += gm[(b << 9) + k] * w1[k * 32 + j];
    t1[t] = elu_f(s);
  }
  __syncthreads();
  if (t < 160) {
    int b = t / 10, j = t - b * 10;
    float s = b2[j];
#pragma unroll
    for (int k = 0; k < 32; k++) s += t1[b * 32 + k] * w2[k * 10 + j];
    out[t] = s;
  }
}

extern "C" void kernel_launch(void* const* d_in, const int* in_sizes, int n_in,
                              void* d_out, int out_size, void* d_ws, size_t ws_size,
                              hipStream_t stream) {
  const float* x   = (const float*)d_in[0];
  const int*   ei  = (const int*)d_in[1];
  const int* batch = (const int*)d_in[2];
  const float* W1  = (const float*)d_in[3];
  const float* as1 = (const float*)d_in[4];
  const float* ad1 = (const float*)d_in[5];
  const float* b1  = (const float*)d_in[6];
  const float* W2  = (const float*)d_in[7];
  const float* as2 = (const float*)d_in[8];
  const float* ad2 = (const float*)d_in[9];
  const float* b2  = (const float*)d_in[10];
  const float* f1w = (const float*)d_in[11];
  const float* f1b = (const float*)d_in[12];
  const float* f2w = (const float*)d_in[13];
  const float* f2b = (const float*)d_in[14];
  float* out = (float*)d_out;

  const int Nn = in_sizes[2];      // 10000
  const int E = in_sizes[1] / 2;   // 160000
  const int Etot = E + Nn;         // self loops appended

  // ---- workspace layout (4B words, 64-word aligned) ----
  size_t off = 0;
  auto alloc = [&](size_t elems) { size_t o = off; off += (elems + 63) & ~(size_t)63; return o; };
  int* wsi = (int*)d_ws;
  float* wsf = (float*)d_ws;

  size_t o_deg  = alloc(Nn);
  size_t o_pool = alloc(16 * 512);
  size_t zero_words = off;               // only deg+pool accumulate -> zero each call
  size_t o_as1  = alloc((size_t)Nn * 8);
  size_t o_ad1  = alloc((size_t)Nn * 8);
  size_t o_as2  = alloc((size_t)Nn * 8);
  size_t o_ad2  = alloc((size_t)Nn * 8);
  size_t o_ps   = alloc(1024);           // P projections [128][8] fp32
  size_t o_pd   = alloc(1024);
  size_t o_bst  = alloc(64);
  size_t o_ben  = alloc(64);
  size_t o_offs = alloc(Nn + 1);
  size_t o_cur  = alloc(Nn);
  size_t o_src  = alloc(Etot);
  size_t o_dst  = alloc(Etot);
  size_t o_psrc = alloc(Etot);
  size_t o_xb   = alloc((size_t)Nn * 128 / 2);   // x bf16  [N,128]
  size_t o_w1t  = alloc(1024 * 128 / 2);         // W1^T bf16 [1024,128]
  size_t o_w2t  = alloc(512 * 1024 / 2);         // W2^T bf16 [512,1024]
  size_t o_s    = alloc((size_t)Nn * 1024 / 2);  // s bf16 [N,1024]
  size_t o_h    = alloc((size_t)Nn * 1024 / 2);  // h2 bf16 [N,512] (first half)
  size_t o_g    = alloc((size_t)Nn * 1024);      // g1 bf16 (first half) then g2 fp32

  ushort_t* xb  = (ushort_t*)(wsi + o_xb);
  ushort_t* w1t = (ushort_t*)(wsi + o_w1t);
  ushort_t* w2t = (ushort_t*)(wsi + o_w2t);
  ushort_t* sb  = (ushort_t*)(wsi + o_s);
  ushort_t* hb  = (ushort_t*)(wsi + o_h);
  ushort_t* g1b = (ushort_t*)(wsi + o_g);

  int eb = (Etot + 255) / 256;
  int ab = (Nn + 255) / 256;  // al1 tail blocks on scatter grid

  int nx4 = Nn * 128 / 4;
  int ep_work = (int)((zero_words > (size_t)nx4 ? zero_words : (size_t)nx4));
  int init_blocks = 648 + (ep_work + 255) / 256;
  init_k<<<init_blocks, 256, 0, stream>>>(wsi, (int)zero_words, x, xb,
                                          W1, w1t, W2, w2t,
                                          as1, ad1, wsf + o_ps, wsf + o_pd, nx4);
  prep_k<<<eb, 256, 0, stream>>>(ei, wsi + o_src, wsi + o_dst, wsi + o_deg,
                                 batch, wsi + o_bst, wsi + o_ben, E, Nn);
  scan_k<<<1, 1024, 0, stream>>>(wsi + o_deg, wsi + o_offs, wsi + o_cur, Nn);
  scatter_k<<<eb + ab, 256, 0, stream>>>(wsi + o_src, wsi + o_dst, wsi + o_cur,
                                         wsi + o_psrc, Etot, eb,
                                         x, wsf + o_ps, wsf + o_pd,
                                         wsf + o_as1, wsf + o_ad1, Nn);

  // ---- layer 1 (restructured): aggregate x; head-blocked GEMM ----
  aggx_k<<<(Nn + 1) / 2, 128, 0, stream>>>(xb, wsf + o_as1, wsf + o_ad1,
                                           wsi + o_offs, wsi + o_psrc, sb, Nn);
  hgemm_k<<<dim3(8, (Nn + 127) / 128), 256, 0, stream>>>(sb, w1t, b1, g1b, Nn);

  // ---- layer 2: 1024 -> 8x64 (BN=64 tile) ----
  mfma_gemm_k<<<dim3(512 / 64, (Nn + 127) / 128), 256, 0, stream>>>(
      g1b, w2t, hb, as2, ad2, wsf + o_as2, wsf + o_ad2, Nn, 512, 1024, 6);
  aggregate_k<512, 6, 64, 2, float><<<(Nn * 2 + 1) / 2, 128, 0, stream>>>(
      hb, wsf + o_as2, wsf + o_ad2, wsi + o_offs, wsi + o_psrc, b2, wsf + o_g, Nn * 2);

  // ---- pool + MLP ----
  pool_k<<<dim3(2, (Nn + 49) / 50), 256, 0, stream>>>(wsf + o_g, batch, wsf + o_pool, Nn);
  mlp_k<<<1, 512, 0, stream>>>(wsf + o_pool, wsi + o_bst, wsi + o_ben, f1w, f1b, f2w, f2b, out);
}

// Round 15
// 248.687 us; speedup vs baseline: 1.6580x; 1.0349x over previous
//
#include <hip/hip_runtime.h>
#include <math.h>

#define HEADS 8
#define NEG 0.2f

typedef unsigned short ushort_t;
typedef __attribute__((ext_vector_type(8))) short short8;
typedef float f32x4 __attribute__((ext_vector_type(4)));

__device__ inline ushort_t f2bf(float f) {
  union { float f; unsigned u; } v; v.f = f;
  unsigned r = (v.u + 0x7FFF + ((v.u >> 16) & 1)) >> 16;  // RNE
  return (ushort_t)r;
}

__device__ inline float4 bf4(uint2 v) {
  union { unsigned u; float f; } a, b, c, d;
  a.u = v.x << 16; b.u = v.x & 0xffff0000u;
  c.u = v.y << 16; d.u = v.y & 0xffff0000u;
  return make_float4(a.f, b.f, c.f, d.f);
}

// fast ELU: exp(v)-1 via hw v_exp_f32; |abs err| ~1e-7, fine vs 1.7e-3 threshold
__device__ inline float elu_f(float v) {
  return (v > 0.f) ? v : (__expf(v) - 1.f);
}

// async global->LDS, 16B per lane; LDS dest is wave-uniform base + lane*16
#define GLDS16(gp, lp)                                                          \
  __builtin_amdgcn_global_load_lds(                                             \
      (const __attribute__((address_space(1))) void*)(gp),                      \
      (__attribute__((address_space(3))) void*)(lp), 16, 0, 0)

// ---- fused init: LDS-tiled W transpose (coalesced both ways) + zero + x->bf16 ----
__global__ __launch_bounds__(256) void init_k(int* __restrict__ ws, int zero_words,
                                              const float* __restrict__ x,
                                              ushort_t* __restrict__ xb,
                                              const float* __restrict__ W1,
                                              ushort_t* __restrict__ w1t,
                                              const float* __restrict__ W2,
                                              ushort_t* __restrict__ w2t, int nx4) {
  __shared__ float tile[32][33];
  int blk = blockIdx.x;
  if (blk < 640) {
    const float* W; ushort_t* Wt; int K, N, tk, tn;
    if (blk < 128) { W = W1; Wt = w1t; K = 128; N = 1024; tk = blk >> 5; tn = blk & 31; }
    else { W = W2; Wt = w2t; K = 1024; N = 512; int t = blk - 128; tk = t >> 4; tn = t & 15; }
    int tx = threadIdx.x & 31, ty = threadIdx.x >> 5;  // 32 x 8
    int k0 = tk * 32, n0 = tn * 32;
#pragma unroll
    for (int r = 0; r < 4; r++)
      tile[ty + r * 8][tx] = W[(size_t)(k0 + ty + r * 8) * N + n0 + tx];  // coalesced read
    __syncthreads();
#pragma unroll
    for (int r = 0; r < 4; r++)
      Wt[(size_t)(n0 + ty + r * 8) * K + k0 + tx] = f2bf(tile[tx][ty + r * 8]);  // coalesced write
  } else {
    int i = (blk - 640) * 256 + threadIdx.x;
    if (i < zero_words) ws[i] = 0;
    if (i < nx4) {
      float4 v = ((const float4*)x)[i];
      ushort_t o[4] = {f2bf(v.x), f2bf(v.y), f2bf(v.z), f2bf(v.w)};
      *(uint2*)&xb[i * 4] = *(uint2*)o;
    }
  }
}

// -- edge prep + degree count + batch bounds fused (batch sorted; no atomics) --
__global__ void prep_k(const int* __restrict__ ei, int* __restrict__ src,
                       int* __restrict__ dst, int* __restrict__ deg,
                       const int* __restrict__ batch, int* __restrict__ bstart,
                       int* __restrict__ bend, int E, int Nn) {
  int i = blockIdx.x * blockDim.x + threadIdx.x;
  if (i < Nn) {
    int b = batch[i];
    if (i == 0 || batch[i - 1] != b) bstart[b] = i;
    if (i == Nn - 1 || batch[i + 1] != b) bend[b] = i + 1;
  }
  if (i >= E + Nn) return;
  int s, d;
  if (i < E) { s = ei[i]; d = ei[E + i]; }
  else       { s = d = i - E; }
  src[i] = s;
  dst[i] = d;
  atomicAdd(&deg[d], 1);
}

// single-block scan over N, 4 elems/thread (4096/chunk), wave-shuffle based
__global__ __launch_bounds__(1024) void scan_k(const int* __restrict__ deg,
                                               int* __restrict__ offs,
                                               int* __restrict__ cursor, int Nn) {
  __shared__ int wtot[16];
  __shared__ int wexcl[16];
  __shared__ int soff_s;
  int t = threadIdx.x;
  int lane = t & 63, w = t >> 6;
  if (t == 0) soff_s = 0;
  __syncthreads();
  for (int base = 0; base < Nn; base += 4096) {
    int idx = base + 4 * t;
    int4 v = make_int4(0, 0, 0, 0);
    if (idx + 3 < Nn) v = *(const int4*)&deg[idx];
    else {
      if (idx < Nn)     v.x = deg[idx];
      if (idx + 1 < Nn) v.y = deg[idx + 1];
      if (idx + 2 < Nn) v.z = deg[idx + 2];
      if (idx + 3 < Nn) v.w = deg[idx + 3];
    }
    int s1 = v.x, s2 = s1 + v.y, s3 = s2 + v.z, s4 = s3 + v.w;
    int sc = s4;  // wave-inclusive scan of per-thread totals
#pragma unroll
    for (int o = 1; o < 64; o <<= 1) {
      int x = __shfl_up(sc, o);
      if (lane >= o) sc += x;
    }
    if (lane == 63) wtot[w] = sc;
    __syncthreads();
    if (w == 0) {
      int tv = (lane < 16) ? wtot[lane] : 0;
      int ts = tv;
#pragma unroll
      for (int o = 1; o < 16; o <<= 1) {
        int x = __shfl_up(ts, o);
        if (lane >= o) ts += x;
      }
      if (lane < 16) wexcl[lane] = ts - tv;
      if (lane == 15) wtot[15] = ts;  // chunk total
    }
    __syncthreads();
    int excl = soff_s + wexcl[w] + (sc - s4);
    int o0 = excl, o1 = excl + s1, o2 = excl + s2, o3 = excl + s3;
    if (idx < Nn)     { offs[idx] = o0;     cursor[idx] = o0; }
    if (idx + 1 < Nn) { offs[idx + 1] = o1; cursor[idx + 1] = o1; }
    if (idx + 2 < Nn) { offs[idx + 2] = o2; cursor[idx + 2] = o2; }
    if (idx + 3 < Nn) { offs[idx + 3] = o3; cursor[idx + 3] = o3; }
    int chunk_total = wtot[15];
    __syncthreads();
    if (t == 0) soff_s += chunk_total;
    __syncthreads();
  }
  if (t == 0) offs[Nn] = soff_s;
}

// scatter src values directly into CSR slot order (no perm indirection)
__global__ void scatter_k(const int* __restrict__ src, const int* __restrict__ dst,
                          int* __restrict__ cursor, int* __restrict__ psrc, int Etot) {
  int i = blockIdx.x * blockDim.x + threadIdx.x;
  if (i >= Etot) return;
  int p = atomicAdd(&cursor[dst[i]], 1);
  psrc[p] = src[i];
}

// ---- P projection: P[k,h] = sum_j W1[k, h*128+j] * att[h,j]  (fp32) ----
__global__ __launch_bounds__(256) void pa_k(const float* __restrict__ W1,
                                            const float* __restrict__ as1,
                                            const float* __restrict__ ad1,
                                            float* __restrict__ Ps,
                                            float* __restrict__ Pd) {
  int h = blockIdx.x;
  int t = threadIdx.x;
  int k = t >> 1, sd = t & 1;
  const float* att = sd ? ad1 : as1;
  float* P = sd ? Pd : Ps;
  const float* wrow = &W1[(size_t)k * 1024 + h * 128];
  const float* arow = &att[h * 128];
  float s = 0.f;
#pragma unroll 8
  for (int c = 0; c < 128; c++) s += wrow[c] * arow[c];
  P[k * 8 + h] = s;
}

// ---- layer-1 alphas via GEMV: asrc1[n,h] = x[n,:] . Ps[:,h]  (all fp32) ----
__global__ __launch_bounds__(256) void al1_k(const float* __restrict__ x,
                                             const float* __restrict__ Ps,
                                             const float* __restrict__ Pd,
                                             float* __restrict__ asrc,
                                             float* __restrict__ adst, int Nn) {
  __shared__ float ps[1024], pd[1024];
  int t = threadIdx.x;
  for (int i = t; i < 1024; i += 256) { ps[i] = Ps[i]; pd[i] = Pd[i]; }
  __syncthreads();
  int n = blockIdx.x * 256 + t;
  if (n >= Nn) return;
  const float4* xr = (const float4*)&x[(size_t)n * 128];
  float as[8], ad[8];
#pragma unroll
  for (int h = 0; h < 8; h++) { as[h] = 0.f; ad[h] = 0.f; }
  for (int k4 = 0; k4 < 32; k4++) {
    float4 xv = xr[k4];
    float xs[4] = {xv.x, xv.y, xv.z, xv.w};
#pragma unroll
    for (int j = 0; j < 4; j++) {
      int k = k4 * 4 + j;
#pragma unroll
      for (int h = 0; h < 8; h++) {
        as[h] += xs[j] * ps[k * 8 + h];   // LDS uniform addr -> broadcast
        ad[h] += xs[j] * pd[k * 8 + h];
      }
    }
  }
#pragma unroll
  for (int h = 0; h < 8; h++) {
    asrc[n * 8 + h] = as[h];
    adst[n * 8 + h] = ad[h];
  }
}

// ---- layer-1 x-side aggregation (gather x 256B/edge, not h 2KB) ----
// 1 block = 1 node, 64 threads (2 channels each). Lane l is weight-producer for
// (edge l>>3, head l&7) of each 8-edge batch; consumers shfl.
__global__ __launch_bounds__(64) void aggx_k(const ushort_t* __restrict__ xb,
                                             const float* __restrict__ asrc,
                                             const float* __restrict__ adst,
                                             const int* __restrict__ offs,
                                             const int* __restrict__ psrc,
                                             ushort_t* __restrict__ sb, int Nn) {
  int n = blockIdx.x;
  int l = threadIdx.x;
  int u_mine = l >> 3, h_mine = l & 7;
  float adn = adst[n * 8 + h_mine];
  int e0 = offs[n], e1 = offs[n + 1];
  int c0 = l * 2;                       // channels 2l, 2l+1
  float acc0[8], acc1[8], wsum[8];
#pragma unroll
  for (int h = 0; h < 8; h++) { acc0[h] = 0.f; acc1[h] = 0.f; wsum[h] = 0.f; }

  for (int i = e0; i < e1; i += 8) {
    int bs = min(8, e1 - i);
    int eu = i + (u_mine < bs ? u_mine : bs - 1);
    int se = psrc[eu];
    float v = asrc[se * 8 + h_mine] + adn;   // 8 nodes x 32B contiguous
    v = (v > 0.f) ? v : NEG * v;             // leaky_relu(0.2)
    float wm = __expf(v);                    // hw v_exp_f32
    int ss[8];
    unsigned xvv[8];
#pragma unroll
    for (int u = 0; u < 8; u++) ss[u] = psrc[i + (u < bs ? u : bs - 1)];
#pragma unroll
    for (int u = 0; u < 8; u++) xvv[u] = *(const unsigned*)&xb[(size_t)ss[u] * 128 + c0];
#pragma unroll
    for (int u = 0; u < 8; u++) {
      if (u < bs) {
        union { unsigned u; float f; } a, b;
        a.u = xvv[u] << 16; b.u = xvv[u] & 0xffff0000u;
#pragma unroll
        for (int h = 0; h < 8; h++) {
          float w = __shfl(wm, (u << 3) | h);
          acc0[h] += w * a.f;
          acc1[h] += w * b.f;
          wsum[h] += w;
        }
      }
    }
  }

#pragma unroll
  for (int h = 0; h < 8; h++) {
    float inv = 1.f / wsum[h];
    unsigned pr = (unsigned)f2bf(acc0[h] * inv) | ((unsigned)f2bf(acc1[h] * inv) << 16);
    *(unsigned*)&sb[(size_t)n * 1024 + h * 128 + c0] = pr;
  }
}

// ---- head-blocked GEMM: g1[n, h*128+j] = elu( s[n,h,:] . W1[:, h*128+j] + b1 ) ----
__global__ __launch_bounds__(256) void hgemm_k(const ushort_t* __restrict__ S,
                                               const ushort_t* __restrict__ Wt,
                                               const float* __restrict__ bias,
                                               ushort_t* __restrict__ G, int M) {
  __shared__ __attribute__((aligned(16))) ushort_t lds[32768];
  int tid = threadIdx.x;
  int lane = tid & 63;
  int wave = tid >> 6;
  int wm = (wave >> 1) * 64, wn = (wave & 1) * 64;
  int head = blockIdx.x;
  int hb0 = head * 128;
  int bm = blockIdx.y * 128;
  int lrow = lane & 15, lq = lane >> 4;

  f32x4 acc[4][4];
#pragma unroll
  for (int i = 0; i < 4; i++)
#pragma unroll
    for (int j = 0; j < 4; j++) acc[i][j] = 0.f;

  int srow = lane >> 3;
  int scol = 8 * ((lane & 7) ^ srow);
  const ushort_t* pa[4];
  const ushort_t* pb[4];
  int lofs[4];
#pragma unroll
  for (int c = 0; c < 4; c++) {
    int row = wave * 32 + c * 8 + srow;
    int ga = min(bm + row, M - 1);
    pa[c] = &S[(size_t)ga * 1024 + hb0 + scol];
    pb[c] = &Wt[(size_t)(hb0 + row) * 128 + scol];
    lofs[c] = (wave * 4 + c) * 512;
  }

  auto stage = [&](int buf, int k0) {
#pragma unroll
    for (int c = 0; c < 4; c++) GLDS16(pa[c] + k0, &lds[buf * 8192 + lofs[c]]);
#pragma unroll
    for (int c = 0; c < 4; c++) GLDS16(pb[c] + k0, &lds[16384 + buf * 8192 + lofs[c]]);
  };
  auto compute = [&](int buf) {
    const ushort_t* Asb = &lds[buf * 8192];
    const ushort_t* Bsb = &lds[16384 + buf * 8192];
#pragma unroll
    for (int ks = 0; ks < 2; ks++) {
      short8 af[4], bfr[4];
#pragma unroll
      for (int t = 0; t < 4; t++) {
        int cbs = (ks * 64 + lq * 16) ^ ((lrow & 7) << 4);
        af[t]  = *(const short8*)&Asb[(wm + t * 16 + lrow) * 64 + (cbs >> 1)];
        bfr[t] = *(const short8*)&Bsb[(wn + t * 16 + lrow) * 64 + (cbs >> 1)];
      }
#pragma unroll
      for (int i = 0; i < 4; i++)
#pragma unroll
        for (int j = 0; j < 4; j++)
          acc[i][j] = __builtin_amdgcn_mfma_f32_16x16x32_bf16(af[i], bfr[j], acc[i][j], 0, 0, 0);
    }
  };

  stage(0, 0);
  asm volatile("s_waitcnt vmcnt(0)" ::: "memory");
  __builtin_amdgcn_s_barrier();
  stage(1, 64);
  compute(0);
  asm volatile("s_waitcnt vmcnt(0)" ::: "memory");
  __builtin_amdgcn_s_barrier();
  compute(1);

  __syncthreads();

  ushort_t* Cl = lds;  // [128][136]
  float bv[4];
#pragma unroll
  for (int j = 0; j < 4; j++) bv[j] = bias[hb0 + wn + j * 16 + lrow];
#pragma unroll
  for (int i = 0; i < 4; i++) {
#pragma unroll
    for (int j = 0; j < 4; j++) {
      int col = wn + j * 16 + lrow;
#pragma unroll
      for (int r = 0; r < 4; r++) {
        int row = wm + i * 16 + lq * 4 + r;
        Cl[row * 136 + col] = f2bf(elu_f(acc[i][j][r] + bv[j]));
      }
    }
  }
  __syncthreads();
#pragma unroll
  for (int p = 0; p < 8; p++) {
    int row = p * 16 + (tid >> 4);
    int col8 = (tid & 15) * 8;
    if (bm + row < M)
      *(uint4*)&G[(size_t)(bm + row) * 1024 + hb0 + col8] = *(const uint4*)&Cl[row * 136 + col8];
  }
}

// ------- bf16 MFMA GEMM + fused alpha epilogue (layer 2 only) -------
__global__ __launch_bounds__(256) void mfma_gemm_k(const ushort_t* __restrict__ A,
                                                   const ushort_t* __restrict__ Bt,
                                                   ushort_t* __restrict__ Cb,
                                                   const float* __restrict__ att_s,
                                                   const float* __restrict__ att_d,
                                                   float* __restrict__ asrc,
                                                   float* __restrict__ adst,
                                                   int M, int N, int K, int CSHIFT) {
  __shared__ __attribute__((aligned(16))) ushort_t lds[32768];  // 64KB, multi-use
  int tid = threadIdx.x;
  int lane = tid & 63;
  int wave = tid >> 6;
  int wm = (wave >> 1) * 64, wn = (wave & 1) * 64;
  int bm = blockIdx.y * 128, bn = blockIdx.x * 128;
  int lrow = lane & 15, lq = lane >> 4;

  f32x4 acc[4][4];
#pragma unroll
  for (int i = 0; i < 4; i++)
#pragma unroll
    for (int j = 0; j < 4; j++) acc[i][j] = 0.f;

  int srow = lane >> 3;
  int scol = 8 * ((lane & 7) ^ srow);
  const ushort_t* pa[4];
  const ushort_t* pb[4];
  int lofs[4];
#pragma unroll
  for (int c = 0; c < 4; c++) {
    int row = wave * 32 + c * 8 + srow;
    int ga = min(bm + row, M - 1);
    pa[c] = &A[(size_t)ga * K + scol];
    pb[c] = &Bt[(size_t)(bn + row) * K + scol];
    lofs[c] = (wave * 4 + c) * 512;
  }

  auto stage = [&](int buf, int k0) {
#pragma unroll
    for (int c = 0; c < 4; c++) GLDS16(pa[c] + k0, &lds[buf * 8192 + lofs[c]]);
#pragma unroll
    for (int c = 0; c < 4; c++) GLDS16(pb[c] + k0, &lds[16384 + buf * 8192 + lofs[c]]);
  };
  auto compute = [&](int buf) {
    const ushort_t* Asb = &lds[buf * 8192];
    const ushort_t* Bsb = &lds[16384 + buf * 8192];
#pragma unroll
    for (int ks = 0; ks < 2; ks++) {
      short8 af[4], bfr[4];
#pragma unroll
      for (int t = 0; t < 4; t++) {
        int cbs = (ks * 64 + lq * 16) ^ ((lrow & 7) << 4);
        af[t]  = *(const short8*)&Asb[(wm + t * 16 + lrow) * 64 + (cbs >> 1)];
        bfr[t] = *(const short8*)&Bsb[(wn + t * 16 + lrow) * 64 + (cbs >> 1)];
      }
#pragma unroll
      for (int i = 0; i < 4; i++)
#pragma unroll
        for (int j = 0; j < 4; j++)
          acc[i][j] = __builtin_amdgcn_mfma_f32_16x16x32_bf16(af[i], bfr[j], acc[i][j], 0, 0, 0);
    }
  };

  int NT = K >> 6;
  stage(0, 0);
  asm volatile("s_waitcnt vmcnt(0)" ::: "memory");
  __builtin_amdgcn_s_barrier();
  int cur = 0;
  for (int t = 0; t + 1 < NT; ++t) {
    stage(cur ^ 1, (t + 1) << 6);
    compute(cur);
    asm volatile("s_waitcnt vmcnt(0)" ::: "memory");
    __builtin_amdgcn_s_barrier();
    cur ^= 1;
  }
  compute(cur);

  __syncthreads();  // safe to alias staging LDS

  ushort_t* Cl = lds;                       // [128][136]
  float* pls = (float*)&lds[17472];
  float* pld = pls + 256;

  {
    float avs[4], avd[4];
#pragma unroll
    for (int j = 0; j < 4; j++) {
      int col = bn + wn + j * 16 + lrow;
      avs[j] = att_s[col];
      avd[j] = att_d[col];
    }
#pragma unroll
    for (int i = 0; i < 4; i++) {
#pragma unroll
      for (int r = 0; r < 4; r++) {
        float ps = 0.f, pd = 0.f;
#pragma unroll
        for (int j = 0; j < 4; j++) {
          float v = acc[i][j][r];
          ps += v * avs[j];
          pd += v * avd[j];
        }
#pragma unroll
        for (int o = 1; o < 16; o <<= 1) {
          ps += __shfl_xor(ps, o);
          pd += __shfl_xor(pd, o);
        }
        if (lrow == 0) {
          int rr = i * 16 + lq * 4 + r;
          pls[wave * 64 + rr] = ps;
          pld[wave * 64 + rr] = pd;
        }
      }
    }
  }

#pragma unroll
  for (int i = 0; i < 4; i++) {
#pragma unroll
    for (int j = 0; j < 4; j++) {
      int col = wn + j * 16 + lrow;
#pragma unroll
      for (int r = 0; r < 4; r++) {
        int row = wm + i * 16 + lq * 4 + r;
        Cl[row * 136 + col] = f2bf(acc[i][j][r]);
      }
    }
  }
  __syncthreads();

#pragma unroll
  for (int p = 0; p < 8; p++) {
    int row = p * 16 + (tid >> 4);
    int col8 = (tid & 15) * 8;
    if (bm + row < M)
      *(uint4*)&Cb[(size_t)(bm + row) * N + bn + col8] = *(const uint4*)&Cl[row * 136 + col8];
  }

  {
    int r = tid & 127, half = tid >> 7;
    if (bm + r < M) {
      const float* P = half ? pld : pls;
      float* O = half ? adst : asrc;
      int w0 = (r >> 6) * 2, idx = r & 63;
      float va = P[w0 * 64 + idx];
      float vb = P[(w0 + 1) * 64 + idx];
      int h0 = bn >> CSHIFT, h1 = (bn + 64) >> CSHIFT;
      size_t base = (size_t)(bm + r) * HEADS;
      if (h0 == h1) O[base + h0] = va + vb;
      else { O[base + h0] = va; O[base + h1] = vb; }
    }
  }
}

// ---- CSR aggregation (layer 2): depth-2 pipelined gathers + wave alpha sharing ----
template <int F, int CSHIFT, int BT, int NSPLIT, typename OT>
__global__ __launch_bounds__(BT) void aggregate_k(const ushort_t* __restrict__ hb,
                                                  const float* __restrict__ asrc,
                                                  const float* __restrict__ adst,
                                                  const int* __restrict__ offs,
                                                  const int* __restrict__ psrc,
                                                  const float* __restrict__ bias,
                                                  OT* __restrict__ out) {
  constexpr int CPB = F / NSPLIT;
  constexpr int G = (1 << CSHIFT) >> 2;
  static_assert(CPB == 4 * BT, "CPB/thread mismatch");
  static_assert(G >= 8 && G <= 64, "head group must cover the 8-edge batch");
  int nb = blockIdx.x;
  int n = nb / NSPLIT;
  int coff = (nb - n * NSPLIT) * CPB;
  int t = threadIdx.x;
  int c0 = coff + 4 * t;
  int hh = c0 >> CSHIFT;
  int lane = t & 63;
  int sub = lane & (G - 1);
  int gb = lane & ~(G - 1);
  float adn = adst[n * HEADS + hh];
  int e0 = offs[n], e1 = offs[n + 1];
  float4 acc = make_float4(0.f, 0.f, 0.f, 0.f);
  float wsum = 0.f;

  int i = e0;
  uint2 rA[8];
  float myWA = 0.f;
  bool haveA = (i + 8 <= e1);
  if (haveA) {
    int sA[8];
#pragma unroll
    for (int u = 0; u < 8; u++) sA[u] = psrc[i + u];
#pragma unroll
    for (int u = 0; u < 8; u++) rA[u] = *(const uint2*)&hb[(size_t)sA[u] * F + c0];
    int ms = psrc[i + (sub < 8 ? sub : 0)];
    float v = asrc[ms * HEADS + hh] + adn;
    v = (v > 0.f) ? v : NEG * v;
    myWA = __expf(v);
  }
  while (i + 16 <= e1) {
    int sB[8];
    uint2 rB[8];
#pragma unroll
    for (int u = 0; u < 8; u++) sB[u] = psrc[i + 8 + u];
#pragma unroll
    for (int u = 0; u < 8; u++) rB[u] = *(const uint2*)&hb[(size_t)sB[u] * F + c0];
    int ms = psrc[i + 8 + (sub < 8 ? sub : 0)];
    float vb = asrc[ms * HEADS + hh] + adn;
    vb = (vb > 0.f) ? vb : NEG * vb;
    float myWB = __expf(vb);
#pragma unroll
    for (int u = 0; u < 8; u++) {
      float w = __shfl(myWA, gb + u);
      float4 f = bf4(rA[u]);
      wsum += w;
      acc.x += w * f.x;
      acc.y += w * f.y;
      acc.z += w * f.z;
      acc.w += w * f.w;
    }
    i += 8;
#pragma unroll
    for (int u = 0; u < 8; u++) rA[u] = rB[u];
    myWA = myWB;
  }
  if (haveA) {
#pragma unroll
    for (int u = 0; u < 8; u++) {
      float w = __shfl(myWA, gb + u);
      float4 f = bf4(rA[u]);
      wsum += w;
      acc.x += w * f.x;
      acc.y += w * f.y;
      acc.z += w * f.z;
      acc.w += w * f.w;
    }
    i += 8;
  }
  for (; i < e1; i++) {
    int ss = psrc[i];
    float v = asrc[ss * HEADS + hh] + adn;
    v = (v > 0.f) ? v : NEG * v;
    float w = __expf(v);
    float4 f = bf4(*(const uint2*)&hb[(size_t)ss * F + c0]);
    wsum += w;
    acc.x += w * f.x; acc.y += w * f.y;
    acc.z += w * f.z; acc.w += w * f.w;
  }

  float inv = 1.f / wsum;
  float v0 = elu_f(acc.x * inv + bias[c0]);
  float v1 = elu_f(acc.y * inv + bias[c0 + 1]);
  float v2 = elu_f(acc.z * inv + bias[c0 + 2]);
  float v3 = elu_f(acc.w * inv + bias[c0 + 3]);
  if constexpr (sizeof(OT) == 2) {
    unsigned p0 = (unsigned)f2bf(v0) | ((unsigned)f2bf(v1) << 16);
    unsigned p1 = (unsigned)f2bf(v2) | ((unsigned)f2bf(v3) << 16);
    *(uint2*)&((ushort_t*)out)[(size_t)n * F + c0] = make_uint2(p0, p1);
  } else {
    *(float4*)&((float*)out)[(size_t)n * F + c0] = make_float4(v0, v1, v2, v3);
  }
}

__global__ __launch_bounds__(256) void pool_k(const float* __restrict__ g,
                                              const int* __restrict__ batch,
                                              float* __restrict__ sums, int Nn) {
  int c = blockIdx.x * 256 + threadIdx.x;  // 0..511
  int n0 = blockIdx.y * 50;
  int n1 = min(n0 + 50, Nn);
  if (n0 >= n1) return;
  float acc = 0.f;
  int cur = batch[n0];
  for (int n = n0; n < n1; n++) {
    int b = batch[n];
    if (b != cur) { atomicAdd(&sums[cur * 512 + c], acc); acc = 0.f; cur = b; }
    acc += g[(size_t)n * 512 + c];
  }
  atomicAdd(&sums[cur * 512 + c], acc);
}

// ---------------- mean + fc1(elu) + fc2, one block ----------------
__global__ __launch_bounds__(512) void mlp_k(const float* __restrict__ sums,
                                             const int* __restrict__ bstart,
                                             const int* __restrict__ bend,
                                             const float* __restrict__ w1,
                                             const float* __restrict__ b1,
                                             const float* __restrict__ w2,
                                             const float* __restrict__ b2,
                                             float* __restrict__ out) {
  __shared__ float gm[16 * 512];
  __shared__ float t1[16 * 32];
  int t = threadIdx.x;
  for (int i = t; i < 16 * 512; i += 512) {
    int b = i >> 9;
    float c = (float)(bend[b] - bstart[b]);
    gm[i] = sums[i] / fmaxf(c, 1.f);
  }
  __syncthreads();
  {
    int b = t >> 5, j = t & 31;
    float s = b1[j];
    for (int k = 0; k < 512; k++) s += gm[(b << 9) + k] * w1[k * 32 + j];
    t1[t] = elu_f(s);
  }
  __syncthreads();
  if (t < 160) {
    int b = t / 10, j = t - b * 10;
    float s = b2[j];
#pragma unroll
    for (int k = 0; k < 32; k++) s += t1[b * 32 + k] * w2[k * 10 + j];
    out[t] = s;
  }
}

extern "C" void kernel_launch(void* const* d_in, const int* in_sizes, int n_in,
                              void* d_out, int out_size, void* d_ws, size_t ws_size,
                              hipStream_t stream) {
  const float* x   = (const float*)d_in[0];
  const int*   ei  = (const int*)d_in[1];
  const int* batch = (const int*)d_in[2];
  const float* W1  = (const float*)d_in[3];
  const float* as1 = (const float*)d_in[4];
  const float* ad1 = (const float*)d_in[5];
  const float* b1  = (const float*)d_in[6];
  const float* W2  = (const float*)d_in[7];
  const float* as2 = (const float*)d_in[8];
  const float* ad2 = (const float*)d_in[9];
  const float* b2  = (const float*)d_in[10];
  const float* f1w = (const float*)d_in[11];
  const float* f1b = (const float*)d_in[12];
  const float* f2w = (const float*)d_in[13];
  const float* f2b = (const float*)d_in[14];
  float* out = (float*)d_out;

  const int Nn = in_sizes[2];      // 10000
  const int E = in_sizes[1] / 2;   // 160000
  const int Etot = E + Nn;         // self loops appended

  // ---- workspace layout (4B words, 64-word aligned) ----
  size_t off = 0;
  auto alloc = [&](size_t elems) { size_t o = off; off += (elems + 63) & ~(size_t)63; return o; };
  int* wsi = (int*)d_ws;
  float* wsf = (float*)d_ws;

  size_t o_deg  = alloc(Nn);
  size_t o_pool = alloc(16 * 512);
  size_t zero_words = off;               // only deg+pool accumulate -> zero each call
  size_t o_as1  = alloc((size_t)Nn * 8);
  size_t o_ad1  = alloc((size_t)Nn * 8);
  size_t o_as2  = alloc((size_t)Nn * 8);
  size_t o_ad2  = alloc((size_t)Nn * 8);
  size_t o_ps   = alloc(1024);           // P projections [128][8] fp32
  size_t o_pd   = alloc(1024);
  size_t o_bst  = alloc(64);
  size_t o_ben  = alloc(64);
  size_t o_offs = alloc(Nn + 1);
  size_t o_cur  = alloc(Nn);
  size_t o_src  = alloc(Etot);
  size_t o_dst  = alloc(Etot);
  size_t o_psrc = alloc(Etot);
  size_t o_xb   = alloc((size_t)Nn * 128 / 2);   // x bf16  [N,128]
  size_t o_w1t  = alloc(1024 * 128 / 2);         // W1^T bf16 [1024,128]
  size_t o_w2t  = alloc(512 * 1024 / 2);         // W2^T bf16 [512,1024]
  size_t o_s    = alloc((size_t)Nn * 1024 / 2);  // s bf16 [N,1024]
  size_t o_h    = alloc((size_t)Nn * 1024 / 2);  // h2 bf16 [N,512] (first half)
  size_t o_g    = alloc((size_t)Nn * 1024);      // g1 bf16 (first half) then g2 fp32

  ushort_t* xb  = (ushort_t*)(wsi + o_xb);
  ushort_t* w1t = (ushort_t*)(wsi + o_w1t);
  ushort_t* w2t = (ushort_t*)(wsi + o_w2t);
  ushort_t* sb  = (ushort_t*)(wsi + o_s);
  ushort_t* hb  = (ushort_t*)(wsi + o_h);
  ushort_t* g1b = (ushort_t*)(wsi + o_g);

  int eb = (Etot + 255) / 256;

  int nx4 = Nn * 128 / 4;
  int ep_work = (int)((zero_words > (size_t)nx4 ? zero_words : (size_t)nx4));
  int init_blocks = 640 + (ep_work + 255) / 256;
  init_k<<<init_blocks, 256, 0, stream>>>(wsi, (int)zero_words, x, xb,
                                          W1, w1t, W2, w2t, nx4);
  prep_k<<<eb, 256, 0, stream>>>(ei, wsi + o_src, wsi + o_dst, wsi + o_deg,
                                 batch, wsi + o_bst, wsi + o_ben, E, Nn);
  scan_k<<<1, 1024, 0, stream>>>(wsi + o_deg, wsi + o_offs, wsi + o_cur, Nn);
  scatter_k<<<eb, 256, 0, stream>>>(wsi + o_src, wsi + o_dst, wsi + o_cur,
                                    wsi + o_psrc, Etot);

  // ---- layer 1 (restructured): alphas via GEMV; aggregate x; head-blocked GEMM ----
  pa_k<<<8, 256, 0, stream>>>(W1, as1, ad1, wsf + o_ps, wsf + o_pd);
  al1_k<<<(Nn + 255) / 256, 256, 0, stream>>>(x, wsf + o_ps, wsf + o_pd,
                                              wsf + o_as1, wsf + o_ad1, Nn);
  aggx_k<<<Nn, 64, 0, stream>>>(xb, wsf + o_as1, wsf + o_ad1,
                                wsi + o_offs, wsi + o_psrc, sb, Nn);
  hgemm_k<<<dim3(8, (Nn + 127) / 128), 256, 0, stream>>>(sb, w1t, b1, g1b, Nn);

  // ---- layer 2: 1024 -> 8x64 ----
  mfma_gemm_k<<<dim3(512 / 128, (Nn + 127) / 128), 256, 0, stream>>>(
      g1b, w2t, hb, as2, ad2, wsf + o_as2, wsf + o_ad2, Nn, 512, 1024, 6);
  aggregate_k<512, 6, 64, 2, float><<<Nn * 2, 64, 0, stream>>>(
      hb, wsf + o_as2, wsf + o_ad2, wsi + o_offs, wsi + o_psrc, b2, wsf + o_g);

  // ---- pool + MLP ----
  pool_k<<<dim3(2, (Nn + 49) / 50), 256, 0, stream>>>(wsf + o_g, batch, wsf + o_pool, Nn);
  mlp_k<<<1, 512, 0, stream>>>(wsf + o_pool, wsi + o_bst, wsi + o_ben, f1w, f1b, f2w, f2b, out);
}